// Round 10
// baseline (696.006 us; speedup 1.0000x reference)
//
#include <hip/hip_runtime.h>
#include <cstdint>
#include <cmath>

#define Bsz  1024
#define Pdim 1024
#define Hdim 4096
#define Ndim 32
#define Ddim 512
#define Ktop 128

typedef _Float16 f16x8  __attribute__((ext_vector_type(8)));
typedef float    f32x16 __attribute__((ext_vector_type(16)));

#define GLDS(gsrc, ldst)                                                        \
  __builtin_amdgcn_global_load_lds(                                             \
      (const __attribute__((address_space(1))) unsigned int*)(gsrc),            \
      (__attribute__((address_space(3))) unsigned int*)(ldst), 16, 0, 0)

// ws layout (time-multiplexed, stream-ordered):
//   phase 1: W images  @0      (16 MB),  pin images @16777216 (4 MB)
//   phase 2: distal images @0  (256 MB), din images @268435456 (2 MB)
// Image per (tile-of-128-rows, K-step-of-32) = 16 KB, FRAGMENT-LINEAR for
// mfma_32x32x16: [hi: frag f=0..7][lo*256: frag f=0..7], frag = 1024 B.
// frag f = ((r&127)>>5)*2 + ((k&31)>>4); within frag lane = (r&31)+32*((k>>3)&1),
// byte = lane*16 + (k&7)*2. (R7/R8-verified layout.)
#define WS_NEEDED 270532608ull

// ---------------------------------------------------------------------------
// convert: fp32 (rows x Krow) -> fragment-linear hi/lo images (R7-verified).
// ---------------------------------------------------------------------------
__global__ __launch_bounds__(256) void convert_img(
    const float* __restrict__ src, char* __restrict__ dst, int kcbits)
{
  const int gid  = blockIdx.x * 256 + threadIdx.x;
  const int row  = gid >> kcbits;
  const int e    = (gid & ((1 << kcbits) - 1)) * 8;
  const int Krow = 8 << kcbits;
  float4 v0 = *(const float4*)(src + (size_t)row * Krow + e);
  float4 v1 = *(const float4*)(src + (size_t)row * Krow + e + 4);
  const int tile = row >> 7, r = row & 127, ks = e >> 5, k = e & 31;
  char* base = dst + (size_t)(tile * (Krow >> 5) + ks) * 16384;
  const int off = ((r >> 5) * 2 + (k >> 4)) * 1024
                + ((r & 31) + 32 * ((k >> 3) & 1)) * 16;
  const float f[8] = {v0.x, v0.y, v0.z, v0.w, v1.x, v1.y, v1.z, v1.w};
  f16x8 hi, lo;
#pragma unroll
  for (int j = 0; j < 8; j++) {
    const _Float16 h = (_Float16)f[j];
    hi[j] = h;
    lo[j] = (_Float16)((f[j] - (float)h) * 256.f);
  }
  *(f16x8*)(base + off)        = hi;
  *(f16x8*)(base + 8192 + off) = lo;
}

// ---------------------------------------------------------------------------
// Barrier-free wave-private pipeline (shared by both MFMA kernels).
// Per wave, per half-step h (K=16):
//   A: own 2 M-frags (hi+lo, 4 KB) GLDS-staged to PRIVATE LDS buf (h&3).
//      GLDS source is PER-LANE (+ lane16 — R9's bug was omitting this);
//      dest is wave-uniform (HW adds lane*16).
//   B: own 2 N-frags (hi+lo) loaded global->VGPR directly (L2-resident).
// Self-sync only: vmcnt(12) leaves {G(h+1),B(h+1),G(h+2)} in flight.
// NO s_barrier anywhere -> waves free-run, pipes overlap.
// ---------------------------------------------------------------------------
#define VMWAIT(N)                                            \
  asm volatile("s_waitcnt vmcnt(" #N ")" ::: "memory");      \
  __builtin_amdgcn_sched_barrier(0)

#define LOADB(H, BH, BL)                                                        \
  { const char* sB = Bwave + (size_t)((H) >> 1) * 16384 + ((H) & 1) * 1024 + lane16; \
    BH[0] = *(const f16x8*)(sB);                                                \
    BH[1] = *(const f16x8*)(sB + 2048);                                         \
    BL[0] = *(const f16x8*)(sB + 8192);                                         \
    BL[1] = *(const f16x8*)(sB + 8192 + 2048);                                  \
    __builtin_amdgcn_sched_barrier(0); }   /* pin B-loads BEFORE the GLDS (FIFO) */

#define STAGE_A(H)                                                              \
  { char* dA = priv + ((H) & 3) * 4096;                                         \
    const char* sA = Awave + (size_t)((H) >> 1) * 16384 + ((H) & 1) * 1024 + lane16; \
    GLDS(sA,                dA);                                                \
    GLDS(sA + 2048,         dA + 1024);                                         \
    GLDS(sA + 8192,         dA + 2048);                                         \
    GLDS(sA + 8192 + 2048,  dA + 3072); }

#define COMPUTE(H, BH, BL)                                                      \
  { const char* buf = priv + ((H) & 3) * 4096 + lane16;                         \
    f16x8 ah[2], al[2];                                                         \
    ah[0] = *(const f16x8*)(buf);                                               \
    ah[1] = *(const f16x8*)(buf + 1024);                                        \
    al[0] = *(const f16x8*)(buf + 2048);                                        \
    al[1] = *(const f16x8*)(buf + 3072);                                        \
    __builtin_amdgcn_s_setprio(1);                                              \
    _Pragma("unroll")                                                           \
    for (int ni = 0; ni < 2; ni++)                                              \
      _Pragma("unroll")                                                         \
      for (int mi = 0; mi < 2; mi++) {                                          \
        acc[mi][ni]  = __builtin_amdgcn_mfma_f32_32x32x16_f16(ah[mi], BH[ni], acc[mi][ni],  0, 0, 0); \
        accx[mi][ni] = __builtin_amdgcn_mfma_f32_32x32x16_f16(ah[mi], BL[ni], accx[mi][ni], 0, 0, 0); \
        accx[mi][ni] = __builtin_amdgcn_mfma_f32_32x32x16_f16(al[mi], BH[ni], accx[mi][ni], 0, 0, 0); \
      }                                                                         \
    __builtin_amdgcn_s_setprio(0); }

// prologue + steady loop + 2-step tail; NH even, >= 4.
#define PIPE_LOOP(NH)                                                           \
  f16x8 bh0[2], bl0[2], bh1[2], bl1[2];                                         \
  LOADB(0, bh0, bl0);                                                           \
  STAGE_A(0); STAGE_A(1);                                                       \
  int h = 0;                                                                    \
  for (; h + 3 < (NH); h += 2) {                                                \
    LOADB(h + 1, bh1, bl1); STAGE_A(h + 2); VMWAIT(12); COMPUTE(h, bh0, bl0);   \
    LOADB(h + 2, bh0, bl0); STAGE_A(h + 3); VMWAIT(12); COMPUTE(h + 1, bh1, bl1); \
  }                                                                             \
  LOADB(h + 1, bh1, bl1); VMWAIT(8); COMPUTE(h, bh0, bl0);                      \
  VMWAIT(0); COMPUTE(h + 1, bh1, bl1);

// ---------------------------------------------------------------------------
// proximal GEMM: C tile 128(h) x 128(b), K=1024 -> NH=64 half-steps.
// ---------------------------------------------------------------------------
__global__ __launch_bounds__(256, 2) void proximal_mfma(
    const char* __restrict__ Aw, const char* __restrict__ Bw,
    const float* __restrict__ bias, float* __restrict__ out)
{
  __shared__ __align__(16) char lds[4][4][4096];  // [wave][buf][4KB]
  const int t = threadIdx.x, lane = t & 63, wv = t >> 6;
  const int lane16 = lane * 16;
  const int hi32 = lane >> 5, c31 = lane & 31;
  const int wr = wv >> 1, wc = wv & 1;
  char* priv = &lds[wv][0][0];

  const int blk = blockIdx.x;
  const int xcd = blk & 7, q = blk >> 3;
  const int htile = xcd * 4 + (q >> 3);   // [0,32)
  const int btile = q & 7;                // [0,8)
  const int h0 = htile * 128, b0 = btile * 128;

  f32x16 acc[2][2], accx[2][2];
#pragma unroll
  for (int mi = 0; mi < 2; mi++)
#pragma unroll
    for (int ni = 0; ni < 2; ni++) {
      acc[mi][ni]  = (f32x16)(0.f);
      accx[mi][ni] = (f32x16)(0.f);
    }

  const char* Awave = Aw + (size_t)(htile * 32) * 16384 + wr * 4096;
  const char* Bwave = Bw + (size_t)(btile * 32) * 16384 + wc * 4096;

  PIPE_LOOP(64)

  // Epilogue: C/D col=lane&31 (b), row=(reg&3)+8*(reg>>2)+4*(lane>>5) (h).
#pragma unroll
  for (int mi = 0; mi < 2; ++mi)
#pragma unroll
    for (int ni = 0; ni < 2; ++ni) {
      const int bcol = b0 + wc * 64 + ni * 32 + c31;
#pragma unroll
      for (int qq = 0; qq < 4; ++qq) {
        const int hb = h0 + wr * 64 + mi * 32 + qq * 8 + hi32 * 4;
        const float4 bb = *(const float4*)(bias + hb);
        float4 o;
        o.x = acc[mi][ni][4*qq+0] + accx[mi][ni][4*qq+0] * 0.00390625f + bb.x;
        o.y = acc[mi][ni][4*qq+1] + accx[mi][ni][4*qq+1] * 0.00390625f + bb.y;
        o.z = acc[mi][ni][4*qq+2] + accx[mi][ni][4*qq+2] * 0.00390625f + bb.z;
        o.w = acc[mi][ni][4*qq+3] + accx[mi][ni][4*qq+3] * 0.00390625f + bb.w;
        *(float4*)(out + (size_t)bcol * Hdim + hb) = o;
      }
    }
}

// ---------------------------------------------------------------------------
// distal GEMM: C tile 128(n') x 128(b), K=512 -> NH=32 half-steps.
// Epilogue: abs-argmax over n (one 32-frag = one h-unit) + gate RMW.
// ---------------------------------------------------------------------------
__global__ __launch_bounds__(256, 2) void distal_mfma(
    const char* __restrict__ Aw, const char* __restrict__ Bw,
    float* __restrict__ out)
{
  __shared__ __align__(16) char lds[4][4][4096];
  const int t = threadIdx.x, lane = t & 63, wv = t >> 6;
  const int lane16 = lane * 16;
  const int hi32 = lane >> 5, c31 = lane & 31;
  const int wr = wv >> 1, wc = wv & 1;
  char* priv = &lds[wv][0][0];

  const int blk = blockIdx.x;
  const int xcd = blk & 7, q = blk >> 3;
  const int ntile = xcd * 128 + (q >> 3);   // [0,1024)
  const int btile = q & 7;                  // [0,8)

  f32x16 acc[2][2], accx[2][2];
#pragma unroll
  for (int mi = 0; mi < 2; mi++)
#pragma unroll
    for (int ni = 0; ni < 2; ni++) {
      acc[mi][ni]  = (f32x16)(0.f);
      accx[mi][ni] = (f32x16)(0.f);
    }

  const char* Awave = Aw + (size_t)(ntile * 16) * 16384 + wr * 4096;
  const char* Bwave = Bw + (size_t)(btile * 16) * 16384 + wc * 4096;

  PIPE_LOOP(32)

  // Epilogue: (wave,mi) owns one h-unit (32 n'-rows = one 32-frag).
  // n(reg) = (reg&3)+8*(reg>>2)+4*hi32 — ascending in reg within a thread;
  // thread scan (strict >) then shfl_xor(32) with first-index tie-break.
#pragma unroll
  for (int mi = 0; mi < 2; ++mi)
#pragma unroll
    for (int ni = 0; ni < 2; ++ni) {
      float bestA = -1.f, bestV = 0.f;
      int   bestN = 999;
#pragma unroll
      for (int reg = 0; reg < 16; ++reg) {
        const float v = acc[mi][ni][reg] + accx[mi][ni][reg] * 0.00390625f;
        const float a = fabsf(v);
        const int   n = (reg & 3) + 8 * (reg >> 2) + 4 * hi32;
        if (a > bestA) { bestA = a; bestV = v; bestN = n; }
      }
      {
        const float oa = __shfl_xor(bestA, 32, 64);
        const float ov = __shfl_xor(bestV, 32, 64);
        const int   on = __shfl_xor(bestN, 32, 64);
        if (oa > bestA || (oa == bestA && on < bestN)) {
          bestA = oa; bestV = ov; bestN = on;
        }
      }
      if (hi32 == 0) {
        const int bcol = btile * 128 + wc * 64 + ni * 32 + c31;
        const int h    = ntile * 4 + wr * 2 + mi;
        const float gate = 1.f / (1.f + expf(-bestV));
        out[(size_t)bcol * Hdim + h] *= gate;
      }
    }
}

// ---------------------------------------------------------------------------
// Fallback fp32 kernels (only if ws is too small; dead on this harness).
// ---------------------------------------------------------------------------
__global__ __launch_bounds__(256) void proximal_gemm(
    const float* __restrict__ pin, const float* __restrict__ W,
    const float* __restrict__ bias, float* __restrict__ out)
{
  __shared__ float Blds[32 * 256];
  __shared__ float Alds[32 * 32];
  const int t  = threadIdx.x;
  const int l  = t & 63;
  const int wv = t >> 6;
  const int ell   = blockIdx.x;
  const int xcd   = ell & 7;
  const int q     = ell >> 3;
  const int htile = xcd * 2 + (q >> 5);
  const int btile = q & 31;
  const int h0 = htile * 256, b0 = btile * 32;

  float acc[8][4];
#pragma unroll
  for (int i = 0; i < 8; i++)
    for (int j = 0; j < 4; j++) acc[i][j] = 0.f;

  const float* wrow = W + (size_t)(h0 + t) * Pdim;
  const int ab = t >> 3, ak = (t & 7) * 4;
  const float* arow = pin + (size_t)(b0 + ab) * Pdim + ak;

  for (int kt = 0; kt < Pdim / 32; ++kt) {
    const int p0 = kt * 32;
    float wbuf[32];
#pragma unroll
    for (int f = 0; f < 8; f++) {
      float4 v = *(const float4*)(wrow + p0 + f * 4);
      wbuf[f * 4 + 0] = v.x; wbuf[f * 4 + 1] = v.y;
      wbuf[f * 4 + 2] = v.z; wbuf[f * 4 + 3] = v.w;
    }
    float4 av = *(const float4*)(arow + p0);
    __syncthreads();
#pragma unroll
    for (int f = 0; f < 32; f++) Blds[f * 256 + t] = wbuf[f];
    Alds[(ak + 0) * 32 + ab] = av.x;
    Alds[(ak + 1) * 32 + ab] = av.y;
    Alds[(ak + 2) * 32 + ab] = av.z;
    Alds[(ak + 3) * 32 + ab] = av.w;
    __syncthreads();
#pragma unroll
    for (int k = 0; k < 32; k++) {
      float4 bv  = *(const float4*)&Blds[k * 256 + 4 * l];
      float4 alo = *(const float4*)&Alds[k * 32 + 8 * wv];
      float4 ahi = *(const float4*)&Alds[k * 32 + 8 * wv + 4];
      float a0[8] = {alo.x, alo.y, alo.z, alo.w, ahi.x, ahi.y, ahi.z, ahi.w};
#pragma unroll
      for (int i = 0; i < 8; i++) {
        acc[i][0] += a0[i] * bv.x;
        acc[i][1] += a0[i] * bv.y;
        acc[i][2] += a0[i] * bv.z;
        acc[i][3] += a0[i] * bv.w;
      }
    }
  }
  float4 bb = *(const float4*)(bias + h0 + 4 * l);
#pragma unroll
  for (int i = 0; i < 8; i++) {
    float4 o;
    o.x = acc[i][0] + bb.x;
    o.y = acc[i][1] + bb.y;
    o.z = acc[i][2] + bb.z;
    o.w = acc[i][3] + bb.w;
    *(float4*)(out + (size_t)(b0 + 8 * wv + i) * Hdim + h0 + 4 * l) = o;
  }
}

__global__ __launch_bounds__(256) void distal_gate_fb(
    const float* __restrict__ din, const float* __restrict__ distal,
    float* __restrict__ out)
{
  __shared__ float Blds[32 * 256];
  __shared__ float Alds[32 * 32];
  const int t  = threadIdx.x;
  const int l  = t & 63;
  const int wv = t >> 6;
  const int ell   = blockIdx.x;
  const int xcd   = ell & 7;
  const int q     = ell >> 3;
  const int htile = xcd * 64 + (q >> 5);
  const int btile = q & 31;
  const int n0 = htile * 256, b0 = btile * 32;

  float acc[8][4];
#pragma unroll
  for (int i = 0; i < 8; i++)
    for (int j = 0; j < 4; j++) acc[i][j] = 0.f;

  const float* brow = distal + (size_t)(n0 + t) * Ddim;
  const int ab = t >> 3, ak = (t & 7) * 4;
  const float* arow = din + (size_t)(b0 + ab) * Ddim + ak;

  for (int kt = 0; kt < Ddim / 32; ++kt) {
    const int d0 = kt * 32;
    float wbuf[32];
#pragma unroll
    for (int f = 0; f < 8; f++) {
      float4 v = *(const float4*)(brow + d0 + f * 4);
      wbuf[f * 4 + 0] = v.x; wbuf[f * 4 + 1] = v.y;
      wbuf[f * 4 + 2] = v.z; wbuf[f * 4 + 3] = v.w;
    }
    float4 av = *(const float4*)(arow + d0);
    __syncthreads();
#pragma unroll
    for (int f = 0; f < 32; f++) Blds[f * 256 + t] = wbuf[f];
    Alds[(ak + 0) * 32 + ab] = av.x;
    Alds[(ak + 1) * 32 + ab] = av.y;
    Alds[(ak + 2) * 32 + ab] = av.z;
    Alds[(ak + 3) * 32 + ab] = av.w;
    __syncthreads();
#pragma unroll
    for (int k = 0; k < 32; k++) {
      float4 bv  = *(const float4*)&Blds[k * 256 + 4 * l];
      float4 alo = *(const float4*)&Alds[k * 32 + 8 * wv];
      float4 ahi = *(const float4*)&Alds[k * 32 + 8 * wv + 4];
      float a0[8] = {alo.x, alo.y, alo.z, alo.w, ahi.x, ahi.y, ahi.z, ahi.w};
#pragma unroll
      for (int i = 0; i < 8; i++) {
        acc[i][0] += a0[i] * bv.x;
        acc[i][1] += a0[i] * bv.y;
        acc[i][2] += a0[i] * bv.z;
        acc[i][3] += a0[i] * bv.w;
      }
    }
  }
  const int i0  = l & 7;
  const int grp = l >> 3;
  float v = 0.f;
#pragma unroll
  for (int bi = 0; bi < 8; bi++) {
    float bav = fabsf(acc[bi][0]);
    float bv_ = acc[bi][0];
    int   bn  = 4 * i0;
#pragma unroll
    for (int j = 1; j < 4; j++) {
      float av2 = fabsf(acc[bi][j]);
      if (av2 > bav) { bav = av2; bv_ = acc[bi][j]; bn = 4 * i0 + j; }
    }
#pragma unroll
    for (int m = 1; m < 8; m <<= 1) {
      float oav = __shfl_xor(bav, m, 64);
      float ov  = __shfl_xor(bv_, m, 64);
      int   on  = __shfl_xor(bn,  m, 64);
      if (oav > bav || (oav == bav && on < bn)) { bav = oav; bv_ = ov; bn = on; }
    }
    if (bi == i0) v = bv_;
  }
  const float gate = 1.f / (1.f + expf(-v));
  const size_t idx = (size_t)(b0 + 8 * wv + i0) * Hdim + (size_t)htile * 8 + grp;
  out[idx] *= gate;
}

// ---------------------------------------------------------------------------
// per-row top-k mask (unchanged, verified R1-R8).
// ---------------------------------------------------------------------------
__device__ __forceinline__ unsigned keyf(float f) {
  unsigned u = __float_as_uint(f);
  return (u & 0x80000000u) ? ~u : (u | 0x80000000u);
}

__global__ __launch_bounds__(256) void topk_mask(float* __restrict__ out)
{
  __shared__ float vals[Hdim];
  __shared__ unsigned hist[256];
  __shared__ unsigned sc[4];
  __shared__ unsigned s_prefix, s_kk;
  const int t = threadIdx.x;
  float* row = out + (size_t)blockIdx.x * Hdim;

#pragma unroll
  for (int qq = 0; qq < 4; qq++) {
    float4 v = *(const float4*)(row + qq * 1024 + t * 4);
    *(float4*)&vals[qq * 1024 + t * 4] = v;
  }
  if (t == 0) { s_prefix = 0u; s_kk = Ktop; }
  __syncthreads();

  for (int shift = 24; shift >= 0; shift -= 8) {
    hist[t] = 0u;
    __syncthreads();
    const unsigned prefix = s_prefix;
    const unsigned maskhi = (shift == 24) ? 0u : (0xFFFFFFFFu << (shift + 8));
    for (int c = 0; c < 16; c++) {
      unsigned u = keyf(vals[c * 256 + t]);
      if ((u & maskhi) == prefix)
        atomicAdd(&hist[(u >> shift) & 255u], 1u);
    }
    __syncthreads();
    if (t == 0) {
      unsigned kk = s_kk, cum = 0;
      int bin = 255;
      for (; bin > 0; --bin) {
        unsigned c = hist[bin];
        if (cum + c >= kk) break;
        cum += c;
      }
      s_kk = kk - cum;
      s_prefix = prefix | ((unsigned)bin << shift);
    }
    __syncthreads();
  }
  const unsigned T  = s_prefix;
  const unsigned kk = s_kk;

  const int lane = t & 63, w = t >> 6;
  unsigned running = 0;
  for (int c = 0; c < 16; c++) {
    const int h = c * 256 + t;
    const float v = vals[h];
    const unsigned u = keyf(v);
    const bool tie = (u == T);
    unsigned long long m = __ballot(tie);
    unsigned lpfx = (unsigned)__popcll(m & ((1ull << lane) - 1ull));
    if (lane == 0) sc[w] = (unsigned)__popcll(m);
    __syncthreads();
    unsigned off = 0;
#pragma unroll
    for (int ww = 0; ww < 4; ww++) if (ww < w) off += sc[ww];
    const unsigned rank = running + off + lpfx;
    row[h] = (u > T) ? v : ((tie && rank < kk) ? v : 0.f);
    const unsigned tot = sc[0] + sc[1] + sc[2] + sc[3];
    __syncthreads();
    running += tot;
  }
}

extern "C" void kernel_launch(void* const* d_in, const int* in_sizes, int n_in,
                              void* d_out, int out_size, void* d_ws, size_t ws_size,
                              hipStream_t stream)
{
  (void)in_sizes; (void)n_in; (void)out_size;
  const float* pin  = (const float*)d_in[0];  // (B,P)
  const float* dinp = (const float*)d_in[1];  // (B,D)
  const float* W    = (const float*)d_in[2];  // (H,P)
  const float* bias = (const float*)d_in[3];  // (H,)
  const float* dst  = (const float*)d_in[4];  // (H,N,D)
  float* out = (float*)d_out;                 // (B,H)

  if (ws_size >= WS_NEEDED) {
    char* ws = (char*)d_ws;
    // phase 1: proximal (W images @0, pin images @16MB — overwritten later)
    hipLaunchKernelGGL(convert_img,   dim3(2048),  dim3(256), 0, stream, W,   ws,             7);
    hipLaunchKernelGGL(convert_img,   dim3(512),   dim3(256), 0, stream, pin, ws + 16777216,  7);
    hipLaunchKernelGGL(proximal_mfma, dim3(256),   dim3(256), 0, stream, ws, ws + 16777216, bias, out);
    // phase 2: distal (distal images @0 overwrite W/pin; din @256MB)
    hipLaunchKernelGGL(convert_img,   dim3(32768), dim3(256), 0, stream, dst,  ws,             6);
    hipLaunchKernelGGL(convert_img,   dim3(256),   dim3(256), 0, stream, dinp, ws + 268435456, 6);
    hipLaunchKernelGGL(distal_mfma,   dim3(8192),  dim3(256), 0, stream, ws, ws + 268435456, out);
  } else {
    hipLaunchKernelGGL(proximal_gemm, dim3(512),   dim3(256), 0, stream, pin, W, bias, out);
    hipLaunchKernelGGL(distal_gate_fb, dim3(16384), dim3(256), 0, stream, dinp, dst, out);
  }

  hipLaunchKernelGGL(topk_mask, dim3(Bsz), dim3(256), 0, stream, out);
}

// Round 11
// 663.957 us; speedup vs baseline: 1.0483x; 1.0483x over previous
//
#include <hip/hip_runtime.h>
#include <cstdint>
#include <cmath>

#define Bsz  1024
#define Pdim 1024
#define Hdim 4096
#define Ndim 32
#define Ddim 512
#define Ktop 128

typedef _Float16 f16x8  __attribute__((ext_vector_type(8)));
typedef float    f32x16 __attribute__((ext_vector_type(16)));

#define GLDS(gsrc, ldst)                                                        \
  __builtin_amdgcn_global_load_lds(                                             \
      (const __attribute__((address_space(1))) unsigned int*)(gsrc),            \
      (__attribute__((address_space(3))) unsigned int*)(ldst), 16, 0, 0)

// ws layout (time-multiplexed, stream-ordered):
//   phase 1: W images  @0      (16 MB),  pin images @16777216 (4 MB)
//   phase 2: distal images @0  (256 MB), din images @268435456 (2 MB)
// Image per (tile-of-128-rows, K-step-of-32) = 16 KB, FRAGMENT-LINEAR for
// mfma_32x32x16: [hi: frag f=0..7][lo*256: frag f=0..7], frag = 1024 B.
// frag f = ((r&127)>>5)*2 + ((k&31)>>4); within frag lane = (r&31)+32*((k>>3)&1),
// byte = lane*16 + (k&7)*2. (R7-R10-verified layout.)
#define WS_NEEDED 270532608ull

// ---------------------------------------------------------------------------
// convert: fp32 (rows x Krow) -> fragment-linear hi/lo images (R7-verified).
// ---------------------------------------------------------------------------
__global__ __launch_bounds__(256) void convert_img(
    const float* __restrict__ src, char* __restrict__ dst, int kcbits)
{
  const int gid  = blockIdx.x * 256 + threadIdx.x;
  const int row  = gid >> kcbits;
  const int e    = (gid & ((1 << kcbits) - 1)) * 8;
  const int Krow = 8 << kcbits;
  float4 v0 = *(const float4*)(src + (size_t)row * Krow + e);
  float4 v1 = *(const float4*)(src + (size_t)row * Krow + e + 4);
  const int tile = row >> 7, r = row & 127, ks = e >> 5, k = e & 31;
  char* base = dst + (size_t)(tile * (Krow >> 5) + ks) * 16384;
  const int off = ((r >> 5) * 2 + (k >> 4)) * 1024
                + ((r & 31) + 32 * ((k >> 3) & 1)) * 16;
  const float f[8] = {v0.x, v0.y, v0.z, v0.w, v1.x, v1.y, v1.z, v1.w};
  f16x8 hi, lo;
#pragma unroll
  for (int j = 0; j < 8; j++) {
    const _Float16 h = (_Float16)f[j];
    hi[j] = h;
    lo[j] = (_Float16)((f[j] - (float)h) * 256.f);
  }
  *(f16x8*)(base + off)        = hi;
  *(f16x8*)(base + 8192 + off) = lo;
}

// ---------------------------------------------------------------------------
// Hybrid pipeline (R8 barrier skeleton + B-in-registers):
//  A: cooperative GLDS staging into 4 x 8KB shared bufs (2 GLDS/wave/half-step,
//     per-lane source + lane16!), published by counted vmcnt + s_barrier.
//  B: per-wave global->VGPR (R10-verified LOADB), prefetched 1 half-step ahead
//     (consumed a full barrier phase later -> L2 latency hidden).
// Steady state: vmcnt(8) keeps {S(h+2):2, B(h+1):4, S(h+1):2} in flight,
// drains B(h)+S(h). Never vmcnt(0) mid-loop. Tail: 6 -> 0.
// ---------------------------------------------------------------------------
#define VMWAIT(N)                                            \
  asm volatile("s_waitcnt vmcnt(" #N ")" ::: "memory");      \
  __builtin_amdgcn_sched_barrier(0)

#define BARRIER()                                            \
  __builtin_amdgcn_s_barrier();                              \
  __builtin_amdgcn_sched_barrier(0)

#define LOADB(H, BH, BL)                                                        \
  { const char* sB = Bwave + (size_t)((H) >> 1) * 16384 + ((H) & 1) * 1024 + lane16; \
    BH[0] = *(const f16x8*)(sB);                                                \
    BH[1] = *(const f16x8*)(sB + 2048);                                         \
    BL[0] = *(const f16x8*)(sB + 8192);                                         \
    BL[1] = *(const f16x8*)(sB + 8192 + 2048);                                  \
    __builtin_amdgcn_sched_barrier(0); }   /* pin B-loads BEFORE the GLDS (FIFO) */

// wave wv stages chunks {2wv, 2wv+1} of the 8 x 1KB A-chunks (hi m0..3, lo m0..3)
#define STAGE_A(H)                                                              \
  { char* buf = &lds[(H) & 3][0];                                               \
    const char* Ai = Abase + (size_t)((H) >> 1) * 16384;                        \
    const int kk = (H) & 1;                                                     \
    _Pragma("unroll")                                                           \
    for (int j = 0; j < 2; j++) {                                               \
      const int ch = wv * 2 + j;                                                \
      const char* src = Ai + (ch >> 2) * 8192 + (2 * (ch & 3) + kk) * 1024 + lane16; \
      GLDS(src, buf + ch * 1024);                                               \
    } }

#define COMPUTE(H, BH, BL)                                                      \
  { const char* buf = &lds[(H) & 3][0] + lane16;                                \
    f16x8 ah[2], al[2];                                                         \
    ah[0] = *(const f16x8*)(buf + (2 * wr + 0) * 1024);                         \
    ah[1] = *(const f16x8*)(buf + (2 * wr + 1) * 1024);                         \
    al[0] = *(const f16x8*)(buf + 4096 + (2 * wr + 0) * 1024);                  \
    al[1] = *(const f16x8*)(buf + 4096 + (2 * wr + 1) * 1024);                  \
    __builtin_amdgcn_s_setprio(1);                                              \
    _Pragma("unroll")                                                           \
    for (int ni = 0; ni < 2; ni++)                                              \
      _Pragma("unroll")                                                         \
      for (int mi = 0; mi < 2; mi++) {                                          \
        acc[mi][ni]  = __builtin_amdgcn_mfma_f32_32x32x16_f16(ah[mi], BH[ni], acc[mi][ni],  0, 0, 0); \
        accx[mi][ni] = __builtin_amdgcn_mfma_f32_32x32x16_f16(ah[mi], BL[ni], accx[mi][ni], 0, 0, 0); \
        accx[mi][ni] = __builtin_amdgcn_mfma_f32_32x32x16_f16(al[mi], BH[ni], accx[mi][ni], 0, 0, 0); \
      }                                                                         \
    __builtin_amdgcn_s_setprio(0); }

// prologue + steady loop (x2 unroll for static B reg double-buffer) + 2-step tail
#define PIPE_LOOP(NH)                                                           \
  f16x8 bh0[2], bl0[2], bh1[2], bl1[2];                                         \
  LOADB(0, bh0, bl0);                                                           \
  STAGE_A(0); STAGE_A(1);                                                       \
  int h = 0;                                                                    \
  for (; h + 3 < (NH); h += 2) {                                                \
    LOADB(h + 1, bh1, bl1); STAGE_A(h + 2); VMWAIT(8); BARRIER();               \
    COMPUTE(h, bh0, bl0);                                                       \
    LOADB(h + 2, bh0, bl0); STAGE_A(h + 3); VMWAIT(8); BARRIER();               \
    COMPUTE(h + 1, bh1, bl1);                                                   \
  }                                                                             \
  LOADB(h + 1, bh1, bl1); VMWAIT(6); BARRIER(); COMPUTE(h, bh0, bl0);           \
  VMWAIT(0); BARRIER(); COMPUTE(h + 1, bh1, bl1);

// ---------------------------------------------------------------------------
// proximal GEMM: C tile 128(h) x 128(b), K=1024 -> NH=64 half-steps.
// ---------------------------------------------------------------------------
__global__ __launch_bounds__(256, 2) void proximal_mfma(
    const char* __restrict__ Aw, const char* __restrict__ Bw,
    const float* __restrict__ bias, float* __restrict__ out)
{
  __shared__ __align__(16) char lds[4][8192];
  const int t = threadIdx.x, lane = t & 63, wv = t >> 6;
  const int lane16 = lane * 16;
  const int hi32 = lane >> 5, c31 = lane & 31;
  const int wr = wv >> 1, wc = wv & 1;

  const int blk = blockIdx.x;
  const int xcd = blk & 7, q = blk >> 3;
  const int htile = xcd * 4 + (q >> 3);   // [0,32)
  const int btile = q & 7;                // [0,8)
  const int h0 = htile * 128, b0 = btile * 128;

  f32x16 acc[2][2], accx[2][2];
#pragma unroll
  for (int mi = 0; mi < 2; mi++)
#pragma unroll
    for (int ni = 0; ni < 2; ni++) {
      acc[mi][ni]  = (f32x16)(0.f);
      accx[mi][ni] = (f32x16)(0.f);
    }

  const char* Abase = Aw + (size_t)(htile * 32) * 16384;
  const char* Bwave = Bw + (size_t)(btile * 32) * 16384 + wc * 4096;

  PIPE_LOOP(64)

  // Epilogue: C/D col=lane&31 (b), row=(reg&3)+8*(reg>>2)+4*(lane>>5) (h).
#pragma unroll
  for (int mi = 0; mi < 2; ++mi)
#pragma unroll
    for (int ni = 0; ni < 2; ++ni) {
      const int bcol = b0 + wc * 64 + ni * 32 + c31;
#pragma unroll
      for (int qq = 0; qq < 4; ++qq) {
        const int hb = h0 + wr * 64 + mi * 32 + qq * 8 + hi32 * 4;
        const float4 bb = *(const float4*)(bias + hb);
        float4 o;
        o.x = acc[mi][ni][4*qq+0] + accx[mi][ni][4*qq+0] * 0.00390625f + bb.x;
        o.y = acc[mi][ni][4*qq+1] + accx[mi][ni][4*qq+1] * 0.00390625f + bb.y;
        o.z = acc[mi][ni][4*qq+2] + accx[mi][ni][4*qq+2] * 0.00390625f + bb.z;
        o.w = acc[mi][ni][4*qq+3] + accx[mi][ni][4*qq+3] * 0.00390625f + bb.w;
        *(float4*)(out + (size_t)bcol * Hdim + hb) = o;
      }
    }
}

// ---------------------------------------------------------------------------
// distal GEMM: C tile 128(n') x 128(b), K=512 -> NH=32 half-steps.
// Epilogue: abs-argmax over n (one 32-frag = one h-unit) + gate RMW.
// ---------------------------------------------------------------------------
__global__ __launch_bounds__(256, 2) void distal_mfma(
    const char* __restrict__ Aw, const char* __restrict__ Bw,
    float* __restrict__ out)
{
  __shared__ __align__(16) char lds[4][8192];
  const int t = threadIdx.x, lane = t & 63, wv = t >> 6;
  const int lane16 = lane * 16;
  const int hi32 = lane >> 5, c31 = lane & 31;
  const int wr = wv >> 1, wc = wv & 1;

  const int blk = blockIdx.x;
  const int xcd = blk & 7, q = blk >> 3;
  const int ntile = xcd * 128 + (q >> 3);   // [0,1024)
  const int btile = q & 7;                  // [0,8)

  f32x16 acc[2][2], accx[2][2];
#pragma unroll
  for (int mi = 0; mi < 2; mi++)
#pragma unroll
    for (int ni = 0; ni < 2; ni++) {
      acc[mi][ni]  = (f32x16)(0.f);
      accx[mi][ni] = (f32x16)(0.f);
    }

  const char* Abase = Aw + (size_t)(ntile * 16) * 16384;
  const char* Bwave = Bw + (size_t)(btile * 16) * 16384 + wc * 4096;

  PIPE_LOOP(32)

  // Epilogue: (wave,mi) owns one h-unit (32 n'-rows = one 32-frag).
  // n(reg) = (reg&3)+8*(reg>>2)+4*hi32 — ascending in reg within a thread;
  // thread scan (strict >) then shfl_xor(32) with first-index tie-break.
#pragma unroll
  for (int mi = 0; mi < 2; ++mi)
#pragma unroll
    for (int ni = 0; ni < 2; ++ni) {
      float bestA = -1.f, bestV = 0.f;
      int   bestN = 999;
#pragma unroll
      for (int reg = 0; reg < 16; ++reg) {
        const float v = acc[mi][ni][reg] + accx[mi][ni][reg] * 0.00390625f;
        const float a = fabsf(v);
        const int   n = (reg & 3) + 8 * (reg >> 2) + 4 * hi32;
        if (a > bestA) { bestA = a; bestV = v; bestN = n; }
      }
      {
        const float oa = __shfl_xor(bestA, 32, 64);
        const float ov = __shfl_xor(bestV, 32, 64);
        const int   on = __shfl_xor(bestN, 32, 64);
        if (oa > bestA || (oa == bestA && on < bestN)) {
          bestA = oa; bestV = ov; bestN = on;
        }
      }
      if (hi32 == 0) {
        const int bcol = btile * 128 + wc * 64 + ni * 32 + c31;
        const int h    = ntile * 4 + wr * 2 + mi;
        const float gate = 1.f / (1.f + expf(-bestV));
        out[(size_t)bcol * Hdim + h] *= gate;
      }
    }
}

// ---------------------------------------------------------------------------
// Fallback fp32 kernels (only if ws is too small; dead on this harness).
// ---------------------------------------------------------------------------
__global__ __launch_bounds__(256) void proximal_gemm(
    const float* __restrict__ pin, const float* __restrict__ W,
    const float* __restrict__ bias, float* __restrict__ out)
{
  __shared__ float Blds[32 * 256];
  __shared__ float Alds[32 * 32];
  const int t  = threadIdx.x;
  const int l  = t & 63;
  const int wv = t >> 6;
  const int ell   = blockIdx.x;
  const int xcd   = ell & 7;
  const int q     = ell >> 3;
  const int htile = xcd * 2 + (q >> 5);
  const int btile = q & 31;
  const int h0 = htile * 256, b0 = btile * 32;

  float acc[8][4];
#pragma unroll
  for (int i = 0; i < 8; i++)
    for (int j = 0; j < 4; j++) acc[i][j] = 0.f;

  const float* wrow = W + (size_t)(h0 + t) * Pdim;
  const int ab = t >> 3, ak = (t & 7) * 4;
  const float* arow = pin + (size_t)(b0 + ab) * Pdim + ak;

  for (int kt = 0; kt < Pdim / 32; ++kt) {
    const int p0 = kt * 32;
    float wbuf[32];
#pragma unroll
    for (int f = 0; f < 8; f++) {
      float4 v = *(const float4*)(wrow + p0 + f * 4);
      wbuf[f * 4 + 0] = v.x; wbuf[f * 4 + 1] = v.y;
      wbuf[f * 4 + 2] = v.z; wbuf[f * 4 + 3] = v.w;
    }
    float4 av = *(const float4*)(arow + p0);
    __syncthreads();
#pragma unroll
    for (int f = 0; f < 32; f++) Blds[f * 256 + t] = wbuf[f];
    Alds[(ak + 0) * 32 + ab] = av.x;
    Alds[(ak + 1) * 32 + ab] = av.y;
    Alds[(ak + 2) * 32 + ab] = av.z;
    Alds[(ak + 3) * 32 + ab] = av.w;
    __syncthreads();
#pragma unroll
    for (int k = 0; k < 32; k++) {
      float4 bv  = *(const float4*)&Blds[k * 256 + 4 * l];
      float4 alo = *(const float4*)&Alds[k * 32 + 8 * wv];
      float4 ahi = *(const float4*)&Alds[k * 32 + 8 * wv + 4];
      float a0[8] = {alo.x, alo.y, alo.z, alo.w, ahi.x, ahi.y, ahi.z, ahi.w};
#pragma unroll
      for (int i = 0; i < 8; i++) {
        acc[i][0] += a0[i] * bv.x;
        acc[i][1] += a0[i] * bv.y;
        acc[i][2] += a0[i] * bv.z;
        acc[i][3] += a0[i] * bv.w;
      }
    }
  }
  float4 bb = *(const float4*)(bias + h0 + 4 * l);
#pragma unroll
  for (int i = 0; i < 8; i++) {
    float4 o;
    o.x = acc[i][0] + bb.x;
    o.y = acc[i][1] + bb.y;
    o.z = acc[i][2] + bb.z;
    o.w = acc[i][3] + bb.w;
    *(float4*)(out + (size_t)(b0 + 8 * wv + i) * Hdim + h0 + 4 * l) = o;
  }
}

__global__ __launch_bounds__(256) void distal_gate_fb(
    const float* __restrict__ din, const float* __restrict__ distal,
    float* __restrict__ out)
{
  __shared__ float Blds[32 * 256];
  __shared__ float Alds[32 * 32];
  const int t  = threadIdx.x;
  const int l  = t & 63;
  const int wv = t >> 6;
  const int ell   = blockIdx.x;
  const int xcd   = ell & 7;
  const int q     = ell >> 3;
  const int htile = xcd * 64 + (q >> 5);
  const int btile = q & 31;
  const int n0 = htile * 256, b0 = btile * 32;

  float acc[8][4];
#pragma unroll
  for (int i = 0; i < 8; i++)
    for (int j = 0; j < 4; j++) acc[i][j] = 0.f;

  const float* brow = distal + (size_t)(n0 + t) * Ddim;
  const int ab = t >> 3, ak = (t & 7) * 4;
  const float* arow = din + (size_t)(b0 + ab) * Ddim + ak;

  for (int kt = 0; kt < Ddim / 32; ++kt) {
    const int d0 = kt * 32;
    float wbuf[32];
#pragma unroll
    for (int f = 0; f < 8; f++) {
      float4 v = *(const float4*)(brow + d0 + f * 4);
      wbuf[f * 4 + 0] = v.x; wbuf[f * 4 + 1] = v.y;
      wbuf[f * 4 + 2] = v.z; wbuf[f * 4 + 3] = v.w;
    }
    float4 av = *(const float4*)(arow + d0);
    __syncthreads();
#pragma unroll
    for (int f = 0; f < 32; f++) Blds[f * 256 + t] = wbuf[f];
    Alds[(ak + 0) * 32 + ab] = av.x;
    Alds[(ak + 1) * 32 + ab] = av.y;
    Alds[(ak + 2) * 32 + ab] = av.z;
    Alds[(ak + 3) * 32 + ab] = av.w;
    __syncthreads();
#pragma unroll
    for (int k = 0; k < 32; k++) {
      float4 bv  = *(const float4*)&Blds[k * 256 + 4 * l];
      float4 alo = *(const float4*)&Alds[k * 32 + 8 * wv];
      float4 ahi = *(const float4*)&Alds[k * 32 + 8 * wv + 4];
      float a0[8] = {alo.x, alo.y, alo.z, alo.w, ahi.x, ahi.y, ahi.z, ahi.w};
#pragma unroll
      for (int i = 0; i < 8; i++) {
        acc[i][0] += a0[i] * bv.x;
        acc[i][1] += a0[i] * bv.y;
        acc[i][2] += a0[i] * bv.z;
        acc[i][3] += a0[i] * bv.w;
      }
    }
  }
  const int i0  = l & 7;
  const int grp = l >> 3;
  float v = 0.f;
#pragma unroll
  for (int bi = 0; bi < 8; bi++) {
    float bav = fabsf(acc[bi][0]);
    float bv_ = acc[bi][0];
    int   bn  = 4 * i0;
#pragma unroll
    for (int j = 1; j < 4; j++) {
      float av2 = fabsf(acc[bi][j]);
      if (av2 > bav) { bav = av2; bv_ = acc[bi][j]; bn = 4 * i0 + j; }
    }
#pragma unroll
    for (int m = 1; m < 8; m <<= 1) {
      float oav = __shfl_xor(bav, m, 64);
      float ov  = __shfl_xor(bv_, m, 64);
      int   on  = __shfl_xor(bn,  m, 64);
      if (oav > bav || (oav == bav && on < bn)) { bav = oav; bv_ = ov; bn = on; }
    }
    if (bi == i0) v = bv_;
  }
  const float gate = 1.f / (1.f + expf(-v));
  const size_t idx = (size_t)(b0 + 8 * wv + i0) * Hdim + (size_t)htile * 8 + grp;
  out[idx] *= gate;
}

// ---------------------------------------------------------------------------
// per-row top-k mask (unchanged, verified R1-R10).
// ---------------------------------------------------------------------------
__device__ __forceinline__ unsigned keyf(float f) {
  unsigned u = __float_as_uint(f);
  return (u & 0x80000000u) ? ~u : (u | 0x80000000u);
}

__global__ __launch_bounds__(256) void topk_mask(float* __restrict__ out)
{
  __shared__ float vals[Hdim];
  __shared__ unsigned hist[256];
  __shared__ unsigned sc[4];
  __shared__ unsigned s_prefix, s_kk;
  const int t = threadIdx.x;
  float* row = out + (size_t)blockIdx.x * Hdim;

#pragma unroll
  for (int qq = 0; qq < 4; qq++) {
    float4 v = *(const float4*)(row + qq * 1024 + t * 4);
    *(float4*)&vals[qq * 1024 + t * 4] = v;
  }
  if (t == 0) { s_prefix = 0u; s_kk = Ktop; }
  __syncthreads();

  for (int shift = 24; shift >= 0; shift -= 8) {
    hist[t] = 0u;
    __syncthreads();
    const unsigned prefix = s_prefix;
    const unsigned maskhi = (shift == 24) ? 0u : (0xFFFFFFFFu << (shift + 8));
    for (int c = 0; c < 16; c++) {
      unsigned u = keyf(vals[c * 256 + t]);
      if ((u & maskhi) == prefix)
        atomicAdd(&hist[(u >> shift) & 255u], 1u);
    }
    __syncthreads();
    if (t == 0) {
      unsigned kk = s_kk, cum = 0;
      int bin = 255;
      for (; bin > 0; --bin) {
        unsigned c = hist[bin];
        if (cum + c >= kk) break;
        cum += c;
      }
      s_kk = kk - cum;
      s_prefix = prefix | ((unsigned)bin << shift);
    }
    __syncthreads();
  }
  const unsigned T  = s_prefix;
  const unsigned kk = s_kk;

  const int lane = t & 63, w = t >> 6;
  unsigned running = 0;
  for (int c = 0; c < 16; c++) {
    const int h = c * 256 + t;
    const float v = vals[h];
    const unsigned u = keyf(v);
    const bool tie = (u == T);
    unsigned long long m = __ballot(tie);
    unsigned lpfx = (unsigned)__popcll(m & ((1ull << lane) - 1ull));
    if (lane == 0) sc[w] = (unsigned)__popcll(m);
    __syncthreads();
    unsigned off = 0;
#pragma unroll
    for (int ww = 0; ww < 4; ww++) if (ww < w) off += sc[ww];
    const unsigned rank = running + off + lpfx;
    row[h] = (u > T) ? v : ((tie && rank < kk) ? v : 0.f);
    const unsigned tot = sc[0] + sc[1] + sc[2] + sc[3];
    __syncthreads();
    running += tot;
  }
}

extern "C" void kernel_launch(void* const* d_in, const int* in_sizes, int n_in,
                              void* d_out, int out_size, void* d_ws, size_t ws_size,
                              hipStream_t stream)
{
  (void)in_sizes; (void)n_in; (void)out_size;
  const float* pin  = (const float*)d_in[0];  // (B,P)
  const float* dinp = (const float*)d_in[1];  // (B,D)
  const float* W    = (const float*)d_in[2];  // (H,P)
  const float* bias = (const float*)d_in[3];  // (H,)
  const float* dst  = (const float*)d_in[4];  // (H,N,D)
  float* out = (float*)d_out;                 // (B,H)

  if (ws_size >= WS_NEEDED) {
    char* ws = (char*)d_ws;
    // phase 1: proximal (W images @0, pin images @16MB — overwritten later)
    hipLaunchKernelGGL(convert_img,   dim3(2048),  dim3(256), 0, stream, W,   ws,             7);
    hipLaunchKernelGGL(convert_img,   dim3(512),   dim3(256), 0, stream, pin, ws + 16777216,  7);
    hipLaunchKernelGGL(proximal_mfma, dim3(256),   dim3(256), 0, stream, ws, ws + 16777216, bias, out);
    // phase 2: distal (distal images @0 overwrite W/pin; din @256MB)
    hipLaunchKernelGGL(convert_img,   dim3(32768), dim3(256), 0, stream, dst,  ws,             6);
    hipLaunchKernelGGL(convert_img,   dim3(256),   dim3(256), 0, stream, dinp, ws + 268435456, 6);
    hipLaunchKernelGGL(distal_mfma,   dim3(8192),  dim3(256), 0, stream, ws, ws + 268435456, out);
  } else {
    hipLaunchKernelGGL(proximal_gemm, dim3(512),   dim3(256), 0, stream, pin, W, bias, out);
    hipLaunchKernelGGL(distal_gate_fb, dim3(16384), dim3(256), 0, stream, dinp, dst, out);
  }

  hipLaunchKernelGGL(topk_mask, dim3(Bsz), dim3(256), 0, stream, out);
}

// Round 12
// 617.379 us; speedup vs baseline: 1.1274x; 1.0754x over previous
//
#include <hip/hip_runtime.h>
#include <cstdint>
#include <cmath>

#define Bsz  1024
#define Pdim 1024
#define Hdim 4096
#define Ndim 32
#define Ddim 512
#define Ktop 128

typedef _Float16 f16x8  __attribute__((ext_vector_type(8)));
typedef float    f32x16 __attribute__((ext_vector_type(16)));

#define GLDS(gsrc, ldst)                                                        \
  __builtin_amdgcn_global_load_lds(                                             \
      (const __attribute__((address_space(1))) unsigned int*)(gsrc),            \
      (__attribute__((address_space(3))) unsigned int*)(ldst), 16, 0, 0)

// ws layout (time-multiplexed, stream-ordered):
//   phase 1: W images  @0      (16 MB),  pin images @16777216 (4 MB)
//   phase 2: distal images @0  (256 MB), din images @268435456 (2 MB)
// Image per (tile-of-128-rows, K-step-of-32) = 16 KB, FRAGMENT-LINEAR for
// mfma_32x32x16: [hi: frag f=0..7][lo*256: frag f=0..7], frag = 1024 B.
// frag f = ((r&127)>>5)*2 + ((k&31)>>4); within frag lane = (r&31)+32*((k>>3)&1),
// byte = lane*16 + (k&7)*2. (R7/R8-verified layout.)
#define WS_NEEDED 270532608ull

// ---------------------------------------------------------------------------
// convert: fp32 (rows x Krow) -> fragment-linear hi/lo images (R7-verified).
// ---------------------------------------------------------------------------
__global__ __launch_bounds__(256) void convert_img(
    const float* __restrict__ src, char* __restrict__ dst, int kcbits)
{
  const int gid  = blockIdx.x * 256 + threadIdx.x;
  const int row  = gid >> kcbits;
  const int e    = (gid & ((1 << kcbits) - 1)) * 8;
  const int Krow = 8 << kcbits;
  float4 v0 = *(const float4*)(src + (size_t)row * Krow + e);
  float4 v1 = *(const float4*)(src + (size_t)row * Krow + e + 4);
  const int tile = row >> 7, r = row & 127, ks = e >> 5, k = e & 31;
  char* base = dst + (size_t)(tile * (Krow >> 5) + ks) * 16384;
  const int off = ((r >> 5) * 2 + (k >> 4)) * 1024
                + ((r & 31) + 32 * ((k >> 3) & 1)) * 16;
  const float f[8] = {v0.x, v0.y, v0.z, v0.w, v1.x, v1.y, v1.z, v1.w};
  f16x8 hi, lo;
#pragma unroll
  for (int j = 0; j < 8; j++) {
    const _Float16 h = (_Float16)f[j];
    hi[j] = h;
    lo[j] = (_Float16)((f[j] - (float)h) * 256.f);
  }
  *(f16x8*)(base + off)        = hi;
  *(f16x8*)(base + 8192 + off) = lo;
}

// ---------------------------------------------------------------------------
// Pipelined half-step GEMM core (R8 structure, verified at 398 us / 51%).
// 4 LDS buffers x 16 KB; half-step h (K=16): buf[h&3] = [A-hi m0..3][A-lo]
// [B-hi][B-lo], 1024B frags. STAGE(h+2) in flight, counted vmcnt (never 0
// mid-loop), raw s_barrier (no drain), 8 ds_read + 12 MFMA per wave.
// NEW (R12): odd blocks take a one-time ~450-cyc s_sleep kick so the two
// co-resident blocks on a CU run in ANTIPHASE: one block's ds_read phase
// overlaps the other's MFMA phase -> LDS and MFMA pipes co-issue instead of
// summing (R8 counters showed wall = LDS + MFMA, i.e. full serialization).
// ---------------------------------------------------------------------------
#define PIPE_LOOP(NH)                                                           \
  STAGE(0);                                                                     \
  STAGE(1);                                                                     \
  for (int h = 0; h < (NH); ++h) {                                              \
    if (h + 2 < (NH)) {                                                         \
      STAGE(h + 2);                                                             \
      asm volatile("s_waitcnt vmcnt(8)" ::: "memory");                          \
    } else if (h + 1 < (NH)) {                                                  \
      asm volatile("s_waitcnt vmcnt(4)" ::: "memory");                          \
    } else {                                                                    \
      asm volatile("s_waitcnt vmcnt(0)" ::: "memory");                          \
    }                                                                           \
    __builtin_amdgcn_s_barrier();                                               \
    asm volatile("" ::: "memory");                                              \
    const char* buf = lds[h & 3];                                               \
    f16x8 ah[2], al[2], bh[2], bl[2];                                           \
    _Pragma("unroll")                                                           \
    for (int mi = 0; mi < 2; mi++) {                                            \
      const int m = wr * 2 + mi;                                                \
      ah[mi] = *(const f16x8*)(buf + m * 1024 + lane16);                        \
      al[mi] = *(const f16x8*)(buf + 4096 + m * 1024 + lane16);                 \
    }                                                                           \
    _Pragma("unroll")                                                           \
    for (int ni = 0; ni < 2; ni++) {                                            \
      const int m = wc * 2 + ni;                                                \
      bh[ni] = *(const f16x8*)(buf + 8192 + m * 1024 + lane16);                 \
      bl[ni] = *(const f16x8*)(buf + 12288 + m * 1024 + lane16);                \
    }                                                                           \
    __builtin_amdgcn_s_setprio(1);                                              \
    _Pragma("unroll")                                                           \
    for (int ni = 0; ni < 2; ni++)                                              \
      _Pragma("unroll")                                                         \
      for (int mi = 0; mi < 2; mi++) {                                          \
        acc[mi][ni]  = __builtin_amdgcn_mfma_f32_32x32x16_f16(ah[mi], bh[ni], acc[mi][ni],  0, 0, 0); \
        accx[mi][ni] = __builtin_amdgcn_mfma_f32_32x32x16_f16(ah[mi], bl[ni], accx[mi][ni], 0, 0, 0); \
        accx[mi][ni] = __builtin_amdgcn_mfma_f32_32x32x16_f16(al[mi], bh[ni], accx[mi][ni], 0, 0, 0); \
      }                                                                         \
    __builtin_amdgcn_s_setprio(0);                                              \
  }

// ---------------------------------------------------------------------------
// proximal GEMM: C tile 128(h) x 128(b), K=1024 -> NH=64 half-steps.
// ---------------------------------------------------------------------------
__global__ __launch_bounds__(256, 2) void proximal_mfma(
    const char* __restrict__ Aw, const char* __restrict__ Bw,
    const float* __restrict__ bias, float* __restrict__ out)
{
  __shared__ __align__(16) char lds[4][16384];
  const int t = threadIdx.x, lane = t & 63, wv = t >> 6;
  const int lane16 = lane * 16;
  const int hi32 = lane >> 5, c31 = lane & 31;
  const int wr = wv >> 1, wc = wv & 1;

  const int blk = blockIdx.x;
  const int xcd = blk & 7, q = blk >> 3;
  const int htile = xcd * 4 + (q >> 3);   // [0,32)
  const int btile = q & 7;                // [0,8)
  const int h0 = htile * 128, b0 = btile * 128;
  if (q & 1) __builtin_amdgcn_s_sleep(7);  // antiphase kick

  f32x16 acc[2][2], accx[2][2];
#pragma unroll
  for (int mi = 0; mi < 2; mi++)
#pragma unroll
    for (int ni = 0; ni < 2; ni++) {
      acc[mi][ni]  = (f32x16)(0.f);
      accx[mi][ni] = (f32x16)(0.f);
    }

  const char* Abase = Aw + (size_t)(htile * 32) * 16384;
  const char* Bbase = Bw + (size_t)(btile * 32) * 16384;

  auto STAGE = [&](int h) {
    const int ks = h >> 1, kk = h & 1;
    char* buf = lds[h & 3];
    const char* Ai = Abase + (size_t)ks * 16384;
    const char* Bi = Bbase + (size_t)ks * 16384;
    const char* srcs[4] = {Ai, Ai + 8192, Bi, Bi + 8192};
#pragma unroll
    for (int j = 0; j < 4; j++) {
      const int c = j * 4 + wv;
      GLDS(srcs[j] + (wv * 2 + kk) * 1024 + lane16, buf + c * 1024);
    }
  };

  PIPE_LOOP(64)

  // Epilogue: C/D col=lane&31 (b), row=(reg&3)+8*(reg>>2)+4*(lane>>5) (h).
#pragma unroll
  for (int mi = 0; mi < 2; ++mi)
#pragma unroll
    for (int ni = 0; ni < 2; ++ni) {
      const int bcol = b0 + wc * 64 + ni * 32 + c31;
#pragma unroll
      for (int qq = 0; qq < 4; ++qq) {
        const int hb = h0 + wr * 64 + mi * 32 + qq * 8 + hi32 * 4;
        const float4 bb = *(const float4*)(bias + hb);
        float4 o;
        o.x = acc[mi][ni][4*qq+0] + accx[mi][ni][4*qq+0] * 0.00390625f + bb.x;
        o.y = acc[mi][ni][4*qq+1] + accx[mi][ni][4*qq+1] * 0.00390625f + bb.y;
        o.z = acc[mi][ni][4*qq+2] + accx[mi][ni][4*qq+2] * 0.00390625f + bb.z;
        o.w = acc[mi][ni][4*qq+3] + accx[mi][ni][4*qq+3] * 0.00390625f + bb.w;
        *(float4*)(out + (size_t)bcol * Hdim + hb) = o;
      }
    }
}

// ---------------------------------------------------------------------------
// distal GEMM: C tile 128(n') x 128(b), K=512 -> NH=32 half-steps.
// Epilogue: abs-argmax over n (one 32-frag = one h-unit) + gate RMW.
// ---------------------------------------------------------------------------
__global__ __launch_bounds__(256, 2) void distal_mfma(
    const char* __restrict__ Aw, const char* __restrict__ Bw,
    float* __restrict__ out)
{
  __shared__ __align__(16) char lds[4][16384];
  const int t = threadIdx.x, lane = t & 63, wv = t >> 6;
  const int lane16 = lane * 16;
  const int hi32 = lane >> 5, c31 = lane & 31;
  const int wr = wv >> 1, wc = wv & 1;

  const int blk = blockIdx.x;
  const int xcd = blk & 7, q = blk >> 3;
  const int ntile = xcd * 128 + (q >> 3);   // [0,1024)
  const int btile = q & 7;                  // [0,8)
  if (q & 1) __builtin_amdgcn_s_sleep(7);   // antiphase kick

  f32x16 acc[2][2], accx[2][2];
#pragma unroll
  for (int mi = 0; mi < 2; mi++)
#pragma unroll
    for (int ni = 0; ni < 2; ni++) {
      acc[mi][ni]  = (f32x16)(0.f);
      accx[mi][ni] = (f32x16)(0.f);
    }

  const char* Abase = Aw + (size_t)(ntile * 16) * 16384;
  const char* Bbase = Bw + (size_t)(btile * 16) * 16384;

  auto STAGE = [&](int h) {
    const int ks = h >> 1, kk = h & 1;
    char* buf = lds[h & 3];
    const char* Ai = Abase + (size_t)ks * 16384;
    const char* Bi = Bbase + (size_t)ks * 16384;
    const char* srcs[4] = {Ai, Ai + 8192, Bi, Bi + 8192};
#pragma unroll
    for (int j = 0; j < 4; j++) {
      const int c = j * 4 + wv;
      GLDS(srcs[j] + (wv * 2 + kk) * 1024 + lane16, buf + c * 1024);
    }
  };

  PIPE_LOOP(32)

  // Epilogue: (wave,mi) owns one h-unit (32 n'-rows = one 32-frag).
  // n(reg) = (reg&3)+8*(reg>>2)+4*hi32 — ascending in reg within a thread;
  // thread scan (strict >) then shfl_xor(32) with first-index tie-break.
#pragma unroll
  for (int mi = 0; mi < 2; ++mi)
#pragma unroll
    for (int ni = 0; ni < 2; ++ni) {
      float bestA = -1.f, bestV = 0.f;
      int   bestN = 999;
#pragma unroll
      for (int reg = 0; reg < 16; ++reg) {
        const float v = acc[mi][ni][reg] + accx[mi][ni][reg] * 0.00390625f;
        const float a = fabsf(v);
        const int   n = (reg & 3) + 8 * (reg >> 2) + 4 * hi32;
        if (a > bestA) { bestA = a; bestV = v; bestN = n; }
      }
      {
        const float oa = __shfl_xor(bestA, 32, 64);
        const float ov = __shfl_xor(bestV, 32, 64);
        const int   on = __shfl_xor(bestN, 32, 64);
        if (oa > bestA || (oa == bestA && on < bestN)) {
          bestA = oa; bestV = ov; bestN = on;
        }
      }
      if (hi32 == 0) {
        const int bcol = btile * 128 + wc * 64 + ni * 32 + c31;
        const int h    = ntile * 4 + wr * 2 + mi;
        const float gate = 1.f / (1.f + expf(-bestV));
        out[(size_t)bcol * Hdim + h] *= gate;
      }
    }
}

// ---------------------------------------------------------------------------
// Fallback fp32 kernels (only if ws is too small; dead on this harness).
// ---------------------------------------------------------------------------
__global__ __launch_bounds__(256) void proximal_gemm(
    const float* __restrict__ pin, const float* __restrict__ W,
    const float* __restrict__ bias, float* __restrict__ out)
{
  __shared__ float Blds[32 * 256];
  __shared__ float Alds[32 * 32];
  const int t  = threadIdx.x;
  const int l  = t & 63;
  const int wv = t >> 6;
  const int ell   = blockIdx.x;
  const int xcd   = ell & 7;
  const int q     = ell >> 3;
  const int htile = xcd * 2 + (q >> 5);
  const int btile = q & 31;
  const int h0 = htile * 256, b0 = btile * 32;

  float acc[8][4];
#pragma unroll
  for (int i = 0; i < 8; i++)
    for (int j = 0; j < 4; j++) acc[i][j] = 0.f;

  const float* wrow = W + (size_t)(h0 + t) * Pdim;
  const int ab = t >> 3, ak = (t & 7) * 4;
  const float* arow = pin + (size_t)(b0 + ab) * Pdim + ak;

  for (int kt = 0; kt < Pdim / 32; ++kt) {
    const int p0 = kt * 32;
    float wbuf[32];
#pragma unroll
    for (int f = 0; f < 8; f++) {
      float4 v = *(const float4*)(wrow + p0 + f * 4);
      wbuf[f * 4 + 0] = v.x; wbuf[f * 4 + 1] = v.y;
      wbuf[f * 4 + 2] = v.z; wbuf[f * 4 + 3] = v.w;
    }
    float4 av = *(const float4*)(arow + p0);
    __syncthreads();
#pragma unroll
    for (int f = 0; f < 32; f++) Blds[f * 256 + t] = wbuf[f];
    Alds[(ak + 0) * 32 + ab] = av.x;
    Alds[(ak + 1) * 32 + ab] = av.y;
    Alds[(ak + 2) * 32 + ab] = av.z;
    Alds[(ak + 3) * 32 + ab] = av.w;
    __syncthreads();
#pragma unroll
    for (int k = 0; k < 32; k++) {
      float4 bv  = *(const float4*)&Blds[k * 256 + 4 * l];
      float4 alo = *(const float4*)&Alds[k * 32 + 8 * wv];
      float4 ahi = *(const float4*)&Alds[k * 32 + 8 * wv + 4];
      float a0[8] = {alo.x, alo.y, alo.z, alo.w, ahi.x, ahi.y, ahi.z, ahi.w};
#pragma unroll
      for (int i = 0; i < 8; i++) {
        acc[i][0] += a0[i] * bv.x;
        acc[i][1] += a0[i] * bv.y;
        acc[i][2] += a0[i] * bv.z;
        acc[i][3] += a0[i] * bv.w;
      }
    }
  }
  float4 bb = *(const float4*)(bias + h0 + 4 * l);
#pragma unroll
  for (int i = 0; i < 8; i++) {
    float4 o;
    o.x = acc[i][0] + bb.x;
    o.y = acc[i][1] + bb.y;
    o.z = acc[i][2] + bb.z;
    o.w = acc[i][3] + bb.w;
    *(float4*)(out + (size_t)(b0 + 8 * wv + i) * Hdim + h0 + 4 * l) = o;
  }
}

__global__ __launch_bounds__(256) void distal_gate_fb(
    const float* __restrict__ din, const float* __restrict__ distal,
    float* __restrict__ out)
{
  __shared__ float Blds[32 * 256];
  __shared__ float Alds[32 * 32];
  const int t  = threadIdx.x;
  const int l  = t & 63;
  const int wv = t >> 6;
  const int ell   = blockIdx.x;
  const int xcd   = ell & 7;
  const int q     = ell >> 3;
  const int htile = xcd * 64 + (q >> 5);
  const int btile = q & 31;
  const int n0 = htile * 256, b0 = btile * 32;

  float acc[8][4];
#pragma unroll
  for (int i = 0; i < 8; i++)
    for (int j = 0; j < 4; j++) acc[i][j] = 0.f;

  const float* brow = distal + (size_t)(n0 + t) * Ddim;
  const int ab = t >> 3, ak = (t & 7) * 4;
  const float* arow = din + (size_t)(b0 + ab) * Ddim + ak;

  for (int kt = 0; kt < Ddim / 32; ++kt) {
    const int d0 = kt * 32;
    float wbuf[32];
#pragma unroll
    for (int f = 0; f < 8; f++) {
      float4 v = *(const float4*)(brow + d0 + f * 4);
      wbuf[f * 4 + 0] = v.x; wbuf[f * 4 + 1] = v.y;
      wbuf[f * 4 + 2] = v.z; wbuf[f * 4 + 3] = v.w;
    }
    float4 av = *(const float4*)(arow + d0);
    __syncthreads();
#pragma unroll
    for (int f = 0; f < 32; f++) Blds[f * 256 + t] = wbuf[f];
    Alds[(ak + 0) * 32 + ab] = av.x;
    Alds[(ak + 1) * 32 + ab] = av.y;
    Alds[(ak + 2) * 32 + ab] = av.z;
    Alds[(ak + 3) * 32 + ab] = av.w;
    __syncthreads();
#pragma unroll
    for (int k = 0; k < 32; k++) {
      float4 bv  = *(const float4*)&Blds[k * 256 + 4 * l];
      float4 alo = *(const float4*)&Alds[k * 32 + 8 * wv];
      float4 ahi = *(const float4*)&Alds[k * 32 + 8 * wv + 4];
      float a0[8] = {alo.x, alo.y, alo.z, alo.w, ahi.x, ahi.y, ahi.z, ahi.w};
#pragma unroll
      for (int i = 0; i < 8; i++) {
        acc[i][0] += a0[i] * bv.x;
        acc[i][1] += a0[i] * bv.y;
        acc[i][2] += a0[i] * bv.z;
        acc[i][3] += a0[i] * bv.w;
      }
    }
  }
  const int i0  = l & 7;
  const int grp = l >> 3;
  float v = 0.f;
#pragma unroll
  for (int bi = 0; bi < 8; bi++) {
    float bav = fabsf(acc[bi][0]);
    float bv_ = acc[bi][0];
    int   bn  = 4 * i0;
#pragma unroll
    for (int j = 1; j < 4; j++) {
      float av2 = fabsf(acc[bi][j]);
      if (av2 > bav) { bav = av2; bv_ = acc[bi][j]; bn = 4 * i0 + j; }
    }
#pragma unroll
    for (int m = 1; m < 8; m <<= 1) {
      float oav = __shfl_xor(bav, m, 64);
      float ov  = __shfl_xor(bv_, m, 64);
      int   on  = __shfl_xor(bn,  m, 64);
      if (oav > bav || (oav == bav && on < bn)) { bav = oav; bv_ = ov; bn = on; }
    }
    if (bi == i0) v = bv_;
  }
  const float gate = 1.f / (1.f + expf(-v));
  const size_t idx = (size_t)(b0 + 8 * wv + i0) * Hdim + (size_t)htile * 8 + grp;
  out[idx] *= gate;
}

// ---------------------------------------------------------------------------
// per-row top-k mask (unchanged, verified R1-R11).
// ---------------------------------------------------------------------------
__device__ __forceinline__ unsigned keyf(float f) {
  unsigned u = __float_as_uint(f);
  return (u & 0x80000000u) ? ~u : (u | 0x80000000u);
}

__global__ __launch_bounds__(256) void topk_mask(float* __restrict__ out)
{
  __shared__ float vals[Hdim];
  __shared__ unsigned hist[256];
  __shared__ unsigned sc[4];
  __shared__ unsigned s_prefix, s_kk;
  const int t = threadIdx.x;
  float* row = out + (size_t)blockIdx.x * Hdim;

#pragma unroll
  for (int qq = 0; qq < 4; qq++) {
    float4 v = *(const float4*)(row + qq * 1024 + t * 4);
    *(float4*)&vals[qq * 1024 + t * 4] = v;
  }
  if (t == 0) { s_prefix = 0u; s_kk = Ktop; }
  __syncthreads();

  for (int shift = 24; shift >= 0; shift -= 8) {
    hist[t] = 0u;
    __syncthreads();
    const unsigned prefix = s_prefix;
    const unsigned maskhi = (shift == 24) ? 0u : (0xFFFFFFFFu << (shift + 8));
    for (int c = 0; c < 16; c++) {
      unsigned u = keyf(vals[c * 256 + t]);
      if ((u & maskhi) == prefix)
        atomicAdd(&hist[(u >> shift) & 255u], 1u);
    }
    __syncthreads();
    if (t == 0) {
      unsigned kk = s_kk, cum = 0;
      int bin = 255;
      for (; bin > 0; --bin) {
        unsigned c = hist[bin];
        if (cum + c >= kk) break;
        cum += c;
      }
      s_kk = kk - cum;
      s_prefix = prefix | ((unsigned)bin << shift);
    }
    __syncthreads();
  }
  const unsigned T  = s_prefix;
  const unsigned kk = s_kk;

  const int lane = t & 63, w = t >> 6;
  unsigned running = 0;
  for (int c = 0; c < 16; c++) {
    const int h = c * 256 + t;
    const float v = vals[h];
    const unsigned u = keyf(v);
    const bool tie = (u == T);
    unsigned long long m = __ballot(tie);
    unsigned lpfx = (unsigned)__popcll(m & ((1ull << lane) - 1ull));
    if (lane == 0) sc[w] = (unsigned)__popcll(m);
    __syncthreads();
    unsigned off = 0;
#pragma unroll
    for (int ww = 0; ww < 4; ww++) if (ww < w) off += sc[ww];
    const unsigned rank = running + off + lpfx;
    row[h] = (u > T) ? v : ((tie && rank < kk) ? v : 0.f);
    const unsigned tot = sc[0] + sc[1] + sc[2] + sc[3];
    __syncthreads();
    running += tot;
  }
}

extern "C" void kernel_launch(void* const* d_in, const int* in_sizes, int n_in,
                              void* d_out, int out_size, void* d_ws, size_t ws_size,
                              hipStream_t stream)
{
  (void)in_sizes; (void)n_in; (void)out_size;
  const float* pin  = (const float*)d_in[0];  // (B,P)
  const float* dinp = (const float*)d_in[1];  // (B,D)
  const float* W    = (const float*)d_in[2];  // (H,P)
  const float* bias = (const float*)d_in[3];  // (H,)
  const float* dst  = (const float*)d_in[4];  // (H,N,D)
  float* out = (float*)d_out;                 // (B,H)

  if (ws_size >= WS_NEEDED) {
    char* ws = (char*)d_ws;
    // phase 1: proximal (W images @0, pin images @16MB — overwritten later)
    hipLaunchKernelGGL(convert_img,   dim3(2048),  dim3(256), 0, stream, W,   ws,             7);
    hipLaunchKernelGGL(convert_img,   dim3(512),   dim3(256), 0, stream, pin, ws + 16777216,  7);
    hipLaunchKernelGGL(proximal_mfma, dim3(256),   dim3(256), 0, stream, ws, ws + 16777216, bias, out);
    // phase 2: distal (distal images @0 overwrite W/pin; din @256MB)
    hipLaunchKernelGGL(convert_img,   dim3(32768), dim3(256), 0, stream, dst,  ws,             6);
    hipLaunchKernelGGL(convert_img,   dim3(256),   dim3(256), 0, stream, dinp, ws + 268435456, 6);
    hipLaunchKernelGGL(distal_mfma,   dim3(8192),  dim3(256), 0, stream, ws, ws + 268435456, out);
  } else {
    hipLaunchKernelGGL(proximal_gemm, dim3(512),   dim3(256), 0, stream, pin, W, bias, out);
    hipLaunchKernelGGL(distal_gate_fb, dim3(16384), dim3(256), 0, stream, dinp, dst, out);
  }

  hipLaunchKernelGGL(topk_mask, dim3(Bsz), dim3(256), 0, stream, out);
}

// Round 13
// 601.729 us; speedup vs baseline: 1.1567x; 1.0260x over previous
//
#include <hip/hip_runtime.h>
#include <cstdint>
#include <cmath>

#define Bsz  1024
#define Pdim 1024
#define Hdim 4096
#define Ndim 32
#define Ddim 512
#define Ktop 128

typedef _Float16 f16x8  __attribute__((ext_vector_type(8)));
typedef float    f32x16 __attribute__((ext_vector_type(16)));

#define GLDS(gsrc, ldst)                                                        \
  __builtin_amdgcn_global_load_lds(                                             \
      (const __attribute__((address_space(1))) unsigned int*)(gsrc),            \
      (__attribute__((address_space(3))) unsigned int*)(ldst), 16, 0, 0)

// Image per (tile-of-128-rows, K-step-of-32) = 16 KB, FRAGMENT-LINEAR for
// mfma_32x32x16: [hi: frag f=0..7][lo*256: frag f=0..7], frag = 1024 B.
// frag f = ((r&127)>>5)*2 + ((k&31)>>4); lane = (r&31)+32*((k>>3)&1),
// byte = lane*16 + (k&7)*2. (R7-R12-verified layout.)
//
// ws layouts:
//  SERIAL (ws >= 258 MB): phase1 W@0(16MB) pin@16MB(4MB); phase2 distal@0
//    (256MB) din@256MB(2MB). Distal gate RMWs out.
//  FUSED (ws >= 294 MB): distal@0(256MB) din@256MB(2MB) W@258MB(16MB)
//    pin@274MB(4MB) gates@278MB(16MB fp32). proximal & distal run in ONE
//    kernel (disjoint outputs: out vs gates); topk applies out*gate.
#define WS_SERIAL 270532608ull
#define OFF_DIN   268435456ull
#define OFF_W     270532608ull
#define OFF_PIN   287309824ull
#define OFF_GATE  291504128ull
#define WS_FUSED  308281344ull

// ---------------------------------------------------------------------------
// convert: fp32 (rows x Krow) -> fragment-linear hi/lo images (R7-verified).
// ---------------------------------------------------------------------------
__global__ __launch_bounds__(256) void convert_img(
    const float* __restrict__ src, char* __restrict__ dst, int kcbits)
{
  const int gid  = blockIdx.x * 256 + threadIdx.x;
  const int row  = gid >> kcbits;
  const int e    = (gid & ((1 << kcbits) - 1)) * 8;
  const int Krow = 8 << kcbits;
  float4 v0 = *(const float4*)(src + (size_t)row * Krow + e);
  float4 v1 = *(const float4*)(src + (size_t)row * Krow + e + 4);
  const int tile = row >> 7, r = row & 127, ks = e >> 5, k = e & 31;
  char* base = dst + (size_t)(tile * (Krow >> 5) + ks) * 16384;
  const int off = ((r >> 5) * 2 + (k >> 4)) * 1024
                + ((r & 31) + 32 * ((k >> 3) & 1)) * 16;
  const float f[8] = {v0.x, v0.y, v0.z, v0.w, v1.x, v1.y, v1.z, v1.w};
  f16x8 hi, lo;
#pragma unroll
  for (int j = 0; j < 8; j++) {
    const _Float16 h = (_Float16)f[j];
    hi[j] = h;
    lo[j] = (_Float16)((f[j] - (float)h) * 256.f);
  }
  *(f16x8*)(base + off)        = hi;
  *(f16x8*)(base + 8192 + off) = lo;
}

// ---------------------------------------------------------------------------
// Two-barrier pipelined GEMM core (m201-style phase ordering):
// per half-step h: [8 ds_read buf[h] | STAGE(h+2) GLDS | bar1 |
//   (lgkm-staggered) 12 MFMA (setprio) | vmcnt(4) | bar2 publishes buf[h+1]].
// Reads are issued BEFORE bar1 so each wave's lgkm wait staggers its MFMA
// start: later waves' LDS reads complete under earlier waves' MFMAs.
// vmcnt ledger: steady outstanding after STAGE(h+2) = {S(h+1):4, S(h+2):4};
// vmcnt(4) after MFMA drains S(h+1) (issued a full iter ago -> ~free).
// Tail: vmcnt(0) at h=NH-2. Never vmcnt(0) in steady loop.
// WAR: buf[(h+2)&3]=buf[(h-2)&3] last read in iter h-2, consumed (lgkm)
// before MFMA(h-2), >=3 barriers before GLDS(h+2) lands. Hoist of reads
// above bar2 blocked by the vmcnt asm "memory" clobber.
// ---------------------------------------------------------------------------
template <int NH>
__device__ __forceinline__ void pipe_gemm(
    char (*lds)[16384], const char* Abase, const char* Bbase,
    int lane16, int wv, int wr, int wc,
    f32x16 acc[2][2], f32x16 accx[2][2])
{
  auto STAGE = [&](int h) {
    const int ks = h >> 1, kk = h & 1;
    char* buf = lds[h & 3];
    const char* Ai = Abase + (size_t)ks * 16384;
    const char* Bi = Bbase + (size_t)ks * 16384;
    const char* srcs[4] = {Ai, Ai + 8192, Bi, Bi + 8192};
#pragma unroll
    for (int j = 0; j < 4; j++) {
      const int c = j * 4 + wv;
      GLDS(srcs[j] + (wv * 2 + kk) * 1024 + lane16, buf + c * 1024);
    }
  };

  STAGE(0);
  STAGE(1);
  asm volatile("s_waitcnt vmcnt(4)" ::: "memory");
  __builtin_amdgcn_s_barrier();
  __builtin_amdgcn_sched_barrier(0);

  for (int h = 0; h < NH; ++h) {
    const char* buf = lds[h & 3];
    f16x8 ah[2], al[2], bh[2], bl[2];
#pragma unroll
    for (int mi = 0; mi < 2; mi++) {
      const int m = wr * 2 + mi;
      ah[mi] = *(const f16x8*)(buf + m * 1024 + lane16);
      al[mi] = *(const f16x8*)(buf + 4096 + m * 1024 + lane16);
    }
#pragma unroll
    for (int ni = 0; ni < 2; ni++) {
      const int m = wc * 2 + ni;
      bh[ni] = *(const f16x8*)(buf + 8192 + m * 1024 + lane16);
      bl[ni] = *(const f16x8*)(buf + 12288 + m * 1024 + lane16);
    }
    __builtin_amdgcn_sched_barrier(0);
    if (h + 2 < NH) STAGE(h + 2);
    __builtin_amdgcn_s_barrier();           // bar1: align; no lgkm wait here
    __builtin_amdgcn_sched_barrier(0);
    __builtin_amdgcn_s_setprio(1);
#pragma unroll
    for (int ni = 0; ni < 2; ni++)
#pragma unroll
      for (int mi = 0; mi < 2; mi++) {
        acc[mi][ni]  = __builtin_amdgcn_mfma_f32_32x32x16_f16(ah[mi], bh[ni], acc[mi][ni],  0, 0, 0);
        accx[mi][ni] = __builtin_amdgcn_mfma_f32_32x32x16_f16(ah[mi], bl[ni], accx[mi][ni], 0, 0, 0);
        accx[mi][ni] = __builtin_amdgcn_mfma_f32_32x32x16_f16(al[mi], bh[ni], accx[mi][ni], 0, 0, 0);
      }
    __builtin_amdgcn_s_setprio(0);
    if (h + 2 < NH) {
      asm volatile("s_waitcnt vmcnt(4)" ::: "memory");
    } else if (h + 1 < NH) {
      asm volatile("s_waitcnt vmcnt(0)" ::: "memory");
    }
    if (h + 1 < NH) {
      __builtin_amdgcn_s_barrier();         // bar2: publishes buf[h+1]
      __builtin_amdgcn_sched_barrier(0);
    }
  }
}

// ---------------------------------------------------------------------------
// Epilogues (R7-R12-verified index math).
// ---------------------------------------------------------------------------
__device__ __forceinline__ void epi_prox(
    f32x16 acc[2][2], f32x16 accx[2][2], const float* bias, float* out,
    int h0, int b0, int wr, int wc, int hi32, int c31)
{
#pragma unroll
  for (int mi = 0; mi < 2; ++mi)
#pragma unroll
    for (int ni = 0; ni < 2; ++ni) {
      const int bcol = b0 + wc * 64 + ni * 32 + c31;
#pragma unroll
      for (int qq = 0; qq < 4; ++qq) {
        const int hb = h0 + wr * 64 + mi * 32 + qq * 8 + hi32 * 4;
        const float4 bb = *(const float4*)(bias + hb);
        float4 o;
        o.x = acc[mi][ni][4*qq+0] + accx[mi][ni][4*qq+0] * 0.00390625f + bb.x;
        o.y = acc[mi][ni][4*qq+1] + accx[mi][ni][4*qq+1] * 0.00390625f + bb.y;
        o.z = acc[mi][ni][4*qq+2] + accx[mi][ni][4*qq+2] * 0.00390625f + bb.z;
        o.w = acc[mi][ni][4*qq+3] + accx[mi][ni][4*qq+3] * 0.00390625f + bb.w;
        *(float4*)(out + (size_t)bcol * Hdim + hb) = o;
      }
    }
}

// abs-argmax over n (one 32-frag = one h-unit), numpy first-index ties.
// gates!=nullptr: write gate; else RMW out.
__device__ __forceinline__ void epi_distal(
    f32x16 acc[2][2], f32x16 accx[2][2], float* out, float* gates,
    int ntile, int btile, int wr, int wc, int hi32, int c31)
{
#pragma unroll
  for (int mi = 0; mi < 2; ++mi)
#pragma unroll
    for (int ni = 0; ni < 2; ++ni) {
      float bestA = -1.f, bestV = 0.f;
      int   bestN = 999;
#pragma unroll
      for (int reg = 0; reg < 16; ++reg) {
        const float v = acc[mi][ni][reg] + accx[mi][ni][reg] * 0.00390625f;
        const float a = fabsf(v);
        const int   n = (reg & 3) + 8 * (reg >> 2) + 4 * hi32;
        if (a > bestA) { bestA = a; bestV = v; bestN = n; }
      }
      {
        const float oa = __shfl_xor(bestA, 32, 64);
        const float ov = __shfl_xor(bestV, 32, 64);
        const int   on = __shfl_xor(bestN, 32, 64);
        if (oa > bestA || (oa == bestA && on < bestN)) {
          bestA = oa; bestV = ov; bestN = on;
        }
      }
      if (hi32 == 0) {
        const int bcol = btile * 128 + wc * 64 + ni * 32 + c31;
        const int h    = ntile * 4 + wr * 2 + mi;
        const float gate = 1.f / (1.f + expf(-bestV));
        const size_t idx = (size_t)bcol * Hdim + h;
        if (gates) gates[idx] = gate;
        else       out[idx] *= gate;
      }
    }
}

// ---------------------------------------------------------------------------
// FUSED kernel: blocks [0,256) = proximal GEMM (writes out);
// blocks [256, 256+8192) = distal GEMM (writes gates). Disjoint outputs.
// ---------------------------------------------------------------------------
__global__ __launch_bounds__(256, 2) void fused_mfma(
    const char* __restrict__ Wimg, const char* __restrict__ Pimg,
    const float* __restrict__ bias, float* __restrict__ out,
    const char* __restrict__ Dimg, const char* __restrict__ Nimg,
    float* __restrict__ gates)
{
  __shared__ __align__(16) char lds[4][16384];
  const int t = threadIdx.x, lane = t & 63, wv = t >> 6;
  const int lane16 = lane * 16;
  const int hi32 = lane >> 5, c31 = lane & 31;
  const int wr = wv >> 1, wc = wv & 1;

  f32x16 acc[2][2], accx[2][2];
#pragma unroll
  for (int mi = 0; mi < 2; mi++)
#pragma unroll
    for (int ni = 0; ni < 2; ni++) {
      acc[mi][ni]  = (f32x16)(0.f);
      accx[mi][ni] = (f32x16)(0.f);
    }

  if (blockIdx.x < 256) {
    const int blk = blockIdx.x;
    const int xcd = blk & 7, q = blk >> 3;
    const int htile = xcd * 4 + (q >> 3);
    const int btile = q & 7;
    pipe_gemm<64>(lds, Wimg + (size_t)(htile * 32) * 16384,
                  Pimg + (size_t)(btile * 32) * 16384,
                  lane16, wv, wr, wc, acc, accx);
    epi_prox(acc, accx, bias, out, htile * 128, btile * 128, wr, wc, hi32, c31);
  } else {
    const int blk = blockIdx.x - 256;
    const int xcd = blk & 7, q = blk >> 3;
    const int ntile = xcd * 128 + (q >> 3);
    const int btile = q & 7;
    pipe_gemm<32>(lds, Dimg + (size_t)(ntile * 16) * 16384,
                  Nimg + (size_t)(btile * 16) * 16384,
                  lane16, wv, wr, wc, acc, accx);
    epi_distal(acc, accx, out, gates, ntile, btile, wr, wc, hi32, c31);
  }
}

// ---------------------------------------------------------------------------
// SERIAL-path kernels (ws in [258MB, 294MB)): same core, R12 launch scheme.
// ---------------------------------------------------------------------------
__global__ __launch_bounds__(256, 2) void proximal_mfma(
    const char* __restrict__ Aw, const char* __restrict__ Bw,
    const float* __restrict__ bias, float* __restrict__ out)
{
  __shared__ __align__(16) char lds[4][16384];
  const int t = threadIdx.x, lane = t & 63, wv = t >> 6;
  const int lane16 = lane * 16;
  const int hi32 = lane >> 5, c31 = lane & 31;
  const int wr = wv >> 1, wc = wv & 1;
  const int blk = blockIdx.x;
  const int xcd = blk & 7, q = blk >> 3;
  const int htile = xcd * 4 + (q >> 3);
  const int btile = q & 7;

  f32x16 acc[2][2], accx[2][2];
#pragma unroll
  for (int mi = 0; mi < 2; mi++)
#pragma unroll
    for (int ni = 0; ni < 2; ni++) {
      acc[mi][ni]  = (f32x16)(0.f);
      accx[mi][ni] = (f32x16)(0.f);
    }
  pipe_gemm<64>(lds, Aw + (size_t)(htile * 32) * 16384,
                Bw + (size_t)(btile * 32) * 16384,
                lane16, wv, wr, wc, acc, accx);
  epi_prox(acc, accx, bias, out, htile * 128, btile * 128, wr, wc, hi32, c31);
}

__global__ __launch_bounds__(256, 2) void distal_mfma(
    const char* __restrict__ Aw, const char* __restrict__ Bw,
    float* __restrict__ out)
{
  __shared__ __align__(16) char lds[4][16384];
  const int t = threadIdx.x, lane = t & 63, wv = t >> 6;
  const int lane16 = lane * 16;
  const int hi32 = lane >> 5, c31 = lane & 31;
  const int wr = wv >> 1, wc = wv & 1;
  const int blk = blockIdx.x;
  const int xcd = blk & 7, q = blk >> 3;
  const int ntile = xcd * 128 + (q >> 3);
  const int btile = q & 7;

  f32x16 acc[2][2], accx[2][2];
#pragma unroll
  for (int mi = 0; mi < 2; mi++)
#pragma unroll
    for (int ni = 0; ni < 2; ni++) {
      acc[mi][ni]  = (f32x16)(0.f);
      accx[mi][ni] = (f32x16)(0.f);
    }
  pipe_gemm<32>(lds, Aw + (size_t)(ntile * 16) * 16384,
                Bw + (size_t)(btile * 16) * 16384,
                lane16, wv, wr, wc, acc, accx);
  epi_distal(acc, accx, out, nullptr, ntile, btile, wr, wc, hi32, c31);
}

// ---------------------------------------------------------------------------
// Fallback fp32 kernels (only if ws is too small; dead on this harness).
// ---------------------------------------------------------------------------
__global__ __launch_bounds__(256) void proximal_gemm(
    const float* __restrict__ pin, const float* __restrict__ W,
    const float* __restrict__ bias, float* __restrict__ out)
{
  __shared__ float Blds[32 * 256];
  __shared__ float Alds[32 * 32];
  const int t  = threadIdx.x;
  const int l  = t & 63;
  const int wv = t >> 6;
  const int ell   = blockIdx.x;
  const int xcd   = ell & 7;
  const int q     = ell >> 3;
  const int htile = xcd * 2 + (q >> 5);
  const int btile = q & 31;
  const int h0 = htile * 256, b0 = btile * 32;

  float acc[8][4];
#pragma unroll
  for (int i = 0; i < 8; i++)
    for (int j = 0; j < 4; j++) acc[i][j] = 0.f;

  const float* wrow = W + (size_t)(h0 + t) * Pdim;
  const int ab = t >> 3, ak = (t & 7) * 4;
  const float* arow = pin + (size_t)(b0 + ab) * Pdim + ak;

  for (int kt = 0; kt < Pdim / 32; ++kt) {
    const int p0 = kt * 32;
    float wbuf[32];
#pragma unroll
    for (int f = 0; f < 8; f++) {
      float4 v = *(const float4*)(wrow + p0 + f * 4);
      wbuf[f * 4 + 0] = v.x; wbuf[f * 4 + 1] = v.y;
      wbuf[f * 4 + 2] = v.z; wbuf[f * 4 + 3] = v.w;
    }
    float4 av = *(const float4*)(arow + p0);
    __syncthreads();
#pragma unroll
    for (int f = 0; f < 32; f++) Blds[f * 256 + t] = wbuf[f];
    Alds[(ak + 0) * 32 + ab] = av.x;
    Alds[(ak + 1) * 32 + ab] = av.y;
    Alds[(ak + 2) * 32 + ab] = av.z;
    Alds[(ak + 3) * 32 + ab] = av.w;
    __syncthreads();
#pragma unroll
    for (int k = 0; k < 32; k++) {
      float4 bv  = *(const float4*)&Blds[k * 256 + 4 * l];
      float4 alo = *(const float4*)&Alds[k * 32 + 8 * wv];
      float4 ahi = *(const float4*)&Alds[k * 32 + 8 * wv + 4];
      float a0[8] = {alo.x, alo.y, alo.z, alo.w, ahi.x, ahi.y, ahi.z, ahi.w};
#pragma unroll
      for (int i = 0; i < 8; i++) {
        acc[i][0] += a0[i] * bv.x;
        acc[i][1] += a0[i] * bv.y;
        acc[i][2] += a0[i] * bv.z;
        acc[i][3] += a0[i] * bv.w;
      }
    }
  }
  float4 bb = *(const float4*)(bias + h0 + 4 * l);
#pragma unroll
  for (int i = 0; i < 8; i++) {
    float4 o;
    o.x = acc[i][0] + bb.x;
    o.y = acc[i][1] + bb.y;
    o.z = acc[i][2] + bb.z;
    o.w = acc[i][3] + bb.w;
    *(float4*)(out + (size_t)(b0 + 8 * wv + i) * Hdim + h0 + 4 * l) = o;
  }
}

__global__ __launch_bounds__(256) void distal_gate_fb(
    const float* __restrict__ din, const float* __restrict__ distal,
    float* __restrict__ out)
{
  __shared__ float Blds[32 * 256];
  __shared__ float Alds[32 * 32];
  const int t  = threadIdx.x;
  const int l  = t & 63;
  const int wv = t >> 6;
  const int ell   = blockIdx.x;
  const int xcd   = ell & 7;
  const int q     = ell >> 3;
  const int htile = xcd * 64 + (q >> 5);
  const int btile = q & 31;
  const int n0 = htile * 256, b0 = btile * 32;

  float acc[8][4];
#pragma unroll
  for (int i = 0; i < 8; i++)
    for (int j = 0; j < 4; j++) acc[i][j] = 0.f;

  const float* brow = distal + (size_t)(n0 + t) * Ddim;
  const int ab = t >> 3, ak = (t & 7) * 4;
  const float* arow = din + (size_t)(b0 + ab) * Ddim + ak;

  for (int kt = 0; kt < Ddim / 32; ++kt) {
    const int d0 = kt * 32;
    float wbuf[32];
#pragma unroll
    for (int f = 0; f < 8; f++) {
      float4 v = *(const float4*)(brow + d0 + f * 4);
      wbuf[f * 4 + 0] = v.x; wbuf[f * 4 + 1] = v.y;
      wbuf[f * 4 + 2] = v.z; wbuf[f * 4 + 3] = v.w;
    }
    float4 av = *(const float4*)(arow + d0);
    __syncthreads();
#pragma unroll
    for (int f = 0; f < 32; f++) Blds[f * 256 + t] = wbuf[f];
    Alds[(ak + 0) * 32 + ab] = av.x;
    Alds[(ak + 1) * 32 + ab] = av.y;
    Alds[(ak + 2) * 32 + ab] = av.z;
    Alds[(ak + 3) * 32 + ab] = av.w;
    __syncthreads();
#pragma unroll
    for (int k = 0; k < 32; k++) {
      float4 bv  = *(const float4*)&Blds[k * 256 + 4 * l];
      float4 alo = *(const float4*)&Alds[k * 32 + 8 * wv];
      float4 ahi = *(const float4*)&Alds[k * 32 + 8 * wv + 4];
      float a0[8] = {alo.x, alo.y, alo.z, alo.w, ahi.x, ahi.y, ahi.z, ahi.w};
#pragma unroll
      for (int i = 0; i < 8; i++) {
        acc[i][0] += a0[i] * bv.x;
        acc[i][1] += a0[i] * bv.y;
        acc[i][2] += a0[i] * bv.z;
        acc[i][3] += a0[i] * bv.w;
      }
    }
  }
  const int i0  = l & 7;
  const int grp = l >> 3;
  float v = 0.f;
#pragma unroll
  for (int bi = 0; bi < 8; bi++) {
    float bav = fabsf(acc[bi][0]);
    float bv_ = acc[bi][0];
    int   bn  = 4 * i0;
#pragma unroll
    for (int j = 1; j < 4; j++) {
      float av2 = fabsf(acc[bi][j]);
      if (av2 > bav) { bav = av2; bv_ = acc[bi][j]; bn = 4 * i0 + j; }
    }
#pragma unroll
    for (int m = 1; m < 8; m <<= 1) {
      float oav = __shfl_xor(bav, m, 64);
      float ov  = __shfl_xor(bv_, m, 64);
      int   on  = __shfl_xor(bn,  m, 64);
      if (oav > bav || (oav == bav && on < bn)) { bav = oav; bv_ = ov; bn = on; }
    }
    if (bi == i0) v = bv_;
  }
  const float gate = 1.f / (1.f + expf(-v));
  const size_t idx = (size_t)(b0 + 8 * wv + i0) * Hdim + (size_t)htile * 8 + grp;
  out[idx] *= gate;
}

// ---------------------------------------------------------------------------
// per-row top-k mask. gates != nullptr: vals = out*gate (fused path);
// else vals = out (serial path, gate already applied). Writes final values.
// ---------------------------------------------------------------------------
__device__ __forceinline__ unsigned keyf(float f) {
  unsigned u = __float_as_uint(f);
  return (u & 0x80000000u) ? ~u : (u | 0x80000000u);
}

__global__ __launch_bounds__(256) void topk_mask(
    float* __restrict__ out, const float* __restrict__ gates)
{
  __shared__ float vals[Hdim];
  __shared__ unsigned hist[256];
  __shared__ unsigned sc[4];
  __shared__ unsigned s_prefix, s_kk;
  const int t = threadIdx.x;
  float* row = out + (size_t)blockIdx.x * Hdim;
  const float* grow = gates ? gates + (size_t)blockIdx.x * Hdim : nullptr;

#pragma unroll
  for (int qq = 0; qq < 4; qq++) {
    float4 v = *(const float4*)(row + qq * 1024 + t * 4);
    if (grow) {
      float4 g = *(const float4*)(grow + qq * 1024 + t * 4);
      v.x *= g.x; v.y *= g.y; v.z *= g.z; v.w *= g.w;
    }
    *(float4*)&vals[qq * 1024 + t * 4] = v;
  }
  if (t == 0) { s_prefix = 0u; s_kk = Ktop; }
  __syncthreads();

  for (int shift = 24; shift >= 0; shift -= 8) {
    hist[t] = 0u;
    __syncthreads();
    const unsigned prefix = s_prefix;
    const unsigned maskhi = (shift == 24) ? 0u : (0xFFFFFFFFu << (shift + 8));
    for (int c = 0; c < 16; c++) {
      unsigned u = keyf(vals[c * 256 + t]);
      if ((u & maskhi) == prefix)
        atomicAdd(&hist[(u >> shift) & 255u], 1u);
    }
    __syncthreads();
    if (t == 0) {
      unsigned kk = s_kk, cum = 0;
      int bin = 255;
      for (; bin > 0; --bin) {
        unsigned c = hist[bin];
        if (cum + c >= kk) break;
        cum += c;
      }
      s_kk = kk - cum;
      s_prefix = prefix | ((unsigned)bin << shift);
    }
    __syncthreads();
  }
  const unsigned T  = s_prefix;
  const unsigned kk = s_kk;

  const int lane = t & 63, w = t >> 6;
  unsigned running = 0;
  for (int c = 0; c < 16; c++) {
    const int h = c * 256 + t;
    const float v = vals[h];
    const unsigned u = keyf(v);
    const bool tie = (u == T);
    unsigned long long m = __ballot(tie);
    unsigned lpfx = (unsigned)__popcll(m & ((1ull << lane) - 1ull));
    if (lane == 0) sc[w] = (unsigned)__popcll(m);
    __syncthreads();
    unsigned off = 0;
#pragma unroll
    for (int ww = 0; ww < 4; ww++) if (ww < w) off += sc[ww];
    const unsigned rank = running + off + lpfx;
    row[h] = (u > T) ? v : ((tie && rank < kk) ? v : 0.f);
    const unsigned tot = sc[0] + sc[1] + sc[2] + sc[3];
    __syncthreads();
    running += tot;
  }
}

extern "C" void kernel_launch(void* const* d_in, const int* in_sizes, int n_in,
                              void* d_out, int out_size, void* d_ws, size_t ws_size,
                              hipStream_t stream)
{
  (void)in_sizes; (void)n_in; (void)out_size;
  const float* pin  = (const float*)d_in[0];  // (B,P)
  const float* dinp = (const float*)d_in[1];  // (B,D)
  const float* W    = (const float*)d_in[2];  // (H,P)
  const float* bias = (const float*)d_in[3];  // (H,)
  const float* dst  = (const float*)d_in[4];  // (H,N,D)
  float* out = (float*)d_out;                 // (B,H)

  char* ws = (char*)d_ws;
  if (ws_size >= WS_FUSED) {
    // fused layout: distal@0, din@256MB, W@258MB, pin@274MB, gates@278MB
    hipLaunchKernelGGL(convert_img, dim3(32768), dim3(256), 0, stream, dst,  ws,            6);
    hipLaunchKernelGGL(convert_img, dim3(256),   dim3(256), 0, stream, dinp, ws + OFF_DIN,  6);
    hipLaunchKernelGGL(convert_img, dim3(2048),  dim3(256), 0, stream, W,    ws + OFF_W,    7);
    hipLaunchKernelGGL(convert_img, dim3(512),   dim3(256), 0, stream, pin,  ws + OFF_PIN,  7);
    hipLaunchKernelGGL(fused_mfma,  dim3(8448),  dim3(256), 0, stream,
                       ws + OFF_W, ws + OFF_PIN, bias, out,
                       ws, ws + OFF_DIN, (float*)(ws + OFF_GATE));
    hipLaunchKernelGGL(topk_mask,   dim3(Bsz),   dim3(256), 0, stream, out,
                       (const float*)(ws + OFF_GATE));
  } else if (ws_size >= WS_SERIAL) {
    // serial layout (R12): phase1 W@0 pin@16MB; phase2 distal@0 din@256MB
    hipLaunchKernelGGL(convert_img,   dim3(2048),  dim3(256), 0, stream, W,   ws,            7);
    hipLaunchKernelGGL(convert_img,   dim3(512),   dim3(256), 0, stream, pin, ws + 16777216, 7);
    hipLaunchKernelGGL(proximal_mfma, dim3(256),   dim3(256), 0, stream, ws, ws + 16777216, bias, out);
    hipLaunchKernelGGL(convert_img,   dim3(32768), dim3(256), 0, stream, dst,  ws,           6);
    hipLaunchKernelGGL(convert_img,   dim3(256),   dim3(256), 0, stream, dinp, ws + OFF_DIN, 6);
    hipLaunchKernelGGL(distal_mfma,   dim3(8192),  dim3(256), 0, stream, ws, ws + OFF_DIN, out);
    hipLaunchKernelGGL(topk_mask,     dim3(Bsz),   dim3(256), 0, stream, out, (const float*)nullptr);
  } else {
    hipLaunchKernelGGL(proximal_gemm,  dim3(512),   dim3(256), 0, stream, pin, W, bias, out);
    hipLaunchKernelGGL(distal_gate_fb, dim3(16384), dim3(256), 0, stream, dinp, dst, out);
    hipLaunchKernelGGL(topk_mask,      dim3(Bsz),   dim3(256), 0, stream, out, (const float*)nullptr);
  }
}